// Round 2
// baseline (2746.988 us; speedup 1.0000x reference)
//
#include <hip/hip_runtime.h>
#include <hip/hip_bf16.h>

#define BN 20736      // 256*81
#define NNODE 81
#define HID 96
#define KNB 20

// ---------------- embed lookup: emb[r][k] = embed[grids[r]][k] ----------------
__global__ __launch_bounds__(256) void embed_lookup_k(const float* __restrict__ embed,
                                                      const int* __restrict__ grids,
                                                      float* __restrict__ emb) {
  int idx = blockIdx.x * 256 + threadIdx.x;
  if (idx >= BN * 16) return;
  int r = idx >> 4, k = idx & 15;
  int g = grids[r];
  emb[idx] = embed[g * 16 + k];
}

// ---------------- generic GEMM: C[M,N] = act(A[M,K] @ W[N,K]^T + bscale*bias + D) ----------------
// A f32 (lda), W f32 (ldw = row stride), bias f32 or null, D f32 (ldd) or null.
__global__ __launch_bounds__(256) void gemm_k(
    const float* __restrict__ A, int lda,
    const float* __restrict__ W, int ldw,
    const float* __restrict__ bias, float bscale,
    const float* __restrict__ D, int ldd,
    float* __restrict__ C, int ldc,
    int M, int N, int K, int act)
{
  __shared__ float As[16][68];
  __shared__ float Ws[16][68];
  const int t = threadIdx.x;
  const int tx = t & 15, ty = t >> 4;
  const int m0 = blockIdx.x * 64, n0 = blockIdx.y * 64;
  float acc[4][4] = {};
  const int kload = t & 15, mload = t >> 4;
  for (int k0 = 0; k0 < K; k0 += 16) {
    #pragma unroll
    for (int p = 0; p < 4; ++p) {
      int mm = mload + p * 16;
      int gm = m0 + mm, gk = k0 + kload;
      As[kload][mm] = (gm < M && gk < K) ? A[(size_t)gm * lda + gk] : 0.f;
      int gn = n0 + mm;
      Ws[kload][mm] = (gn < N && gk < K) ? W[(size_t)gn * ldw + gk] : 0.f;
    }
    __syncthreads();
    #pragma unroll
    for (int k = 0; k < 16; ++k) {
      float4 a4 = *(const float4*)&As[k][4 * ty];
      float4 w4 = *(const float4*)&Ws[k][4 * tx];
      float av[4] = {a4.x, a4.y, a4.z, a4.w};
      float wv[4] = {w4.x, w4.y, w4.z, w4.w};
      #pragma unroll
      for (int im = 0; im < 4; ++im)
        #pragma unroll
        for (int jn = 0; jn < 4; ++jn)
          acc[im][jn] += av[im] * wv[jn];
    }
    __syncthreads();
  }
  #pragma unroll
  for (int im = 0; im < 4; ++im) {
    int m = m0 + 4 * ty + im;
    if (m >= M) continue;
    #pragma unroll
    for (int jn = 0; jn < 4; ++jn) {
      int n = n0 + 4 * tx + jn;
      if (n >= N) continue;
      float v = acc[im][jn];
      if (bias) v += bscale * bias[n];
      if (D) v += D[(size_t)m * ldd + n];
      if (act == 1) v = fmaxf(v, 0.f);
      C[(size_t)m * ldc + n] = v;
    }
  }
}

// ---------------- fused edge-message kernel ----------------
// S[row][o] = sum_j relu( dot(W1[o,:], relu(A_s[row] + A_n[nbr_j] + b0)) + b1[o] )
// block = 192 threads (2 edge slots x 96 outputs), 4 nodes per block.
__global__ __launch_bounds__(192) void edge_msg_k(
    const float* __restrict__ As_, const float* __restrict__ An_,
    const float* __restrict__ W1, const float* __restrict__ b0,
    const float* __restrict__ b1, const int* __restrict__ edges,
    float* __restrict__ S)
{
  __shared__ float W1s[96][100];
  __shared__ float z1s[2][96];
  __shared__ float accs[2][96];
  __shared__ float b0s[96], b1s[96], asrow[96];
  const int t = threadIdx.x;
  for (int i = t; i < 96 * 96; i += 192) W1s[i / 96][i % 96] = W1[i];
  if (t < 96) { b0s[t] = b0[t]; b1s[t] = b1[t]; }
  const int slot = t / 96;
  const int o = t - slot * 96;
  for (int nb = 0; nb < 4; ++nb) {
    int row = blockIdx.x * 4 + nb;
    int b = row / NNODE, i = row - b * NNODE;
    __syncthreads();                       // covers W1 staging (nb=0) and prev-node reuse
    if (t < 96) asrow[t] = As_[(size_t)row * HID + t];
    __syncthreads();
    float acc = 0.f;
    for (int jp = 0; jp < 10; ++jp) {
      int j = jp * 2 + slot;
      int e = edges[i * KNB + j];
      const float* an = An_ + ((size_t)b * NNODE + e) * HID;
      z1s[slot][o] = fmaxf(asrow[o] + an[o] + b0s[o], 0.f);
      __syncthreads();
      float d = b1s[o];
      #pragma unroll
      for (int k = 0; k < 96; ++k) d += W1s[o][k] * z1s[slot][k];
      acc += fmaxf(d, 0.f);
      __syncthreads();
    }
    accs[slot][o] = acc;
    __syncthreads();
    if (slot == 0) S[(size_t)row * HID + o] = accs[0][o] + accs[1][o];
  }
}

// ---------------- LSTM cell elementwise ----------------
__global__ __launch_bounds__(256) void lstm_k(const float* __restrict__ gates,
                                              float* __restrict__ c, float* __restrict__ H) {
  int idx = blockIdx.x * 256 + threadIdx.x;
  if (idx >= BN * HID) return;
  int r = idx / HID, k = idx - r * HID;
  const float* g = gates + (size_t)r * 384;
  float gi = g[k], gf = g[96 + k], gg = g[192 + k], go = g[288 + k];
  float si = 1.f / (1.f + expf(-gi));
  float sf = 1.f / (1.f + expf(-gf));
  float so = 1.f / (1.f + expf(-go));
  float tg = tanhf(gg);
  float cn = sf * c[idx] + si * tg;
  c[idx] = cn;
  H[idx] = so * tanhf(cn);
}

// ---------------- host side ----------------
static inline void run_gemm(hipStream_t s, const float* A, int lda, const float* W, int ldw,
                            const float* bias, float bscale, const float* D, int ldd,
                            float* C, int ldc, int M, int N, int K, int act) {
  dim3 grid((M + 63) / 64, (N + 63) / 64);
  gemm_k<<<grid, 256, 0, s>>>(A, lda, W, ldw, bias, bscale, D, ldd, C, ldc, M, N, K, act);
}

extern "C" void kernel_launch(void* const* d_in, const int* in_sizes, int n_in,
                              void* d_out, int out_size, void* d_ws, size_t ws_size,
                              hipStream_t stream) {
  const float* embed   = (const float*)d_in[0];
  const float* in_w0   = (const float*)d_in[1];
  const float* in_b0   = (const float*)d_in[2];
  const float* in_w1   = (const float*)d_in[3];
  const float* in_b1   = (const float*)d_in[4];
  const float* in_w2   = (const float*)d_in[5];
  const float* in_b2   = (const float*)d_in[6];
  const float* f_w0    = (const float*)d_in[7];
  const float* f_b0    = (const float*)d_in[8];
  const float* f_w1    = (const float*)d_in[9];
  const float* f_b1    = (const float*)d_in[10];
  const float* f_w2    = (const float*)d_in[11];
  const float* f_b2    = (const float*)d_in[12];
  const float* g_w0    = (const float*)d_in[13];
  const float* g_b0    = (const float*)d_in[14];
  const float* g_w1    = (const float*)d_in[15];
  const float* g_b1    = (const float*)d_in[16];
  const float* g_w2    = (const float*)d_in[17];
  const float* g_b2    = (const float*)d_in[18];
  const float* wih     = (const float*)d_in[19];
  const float* whh     = (const float*)d_in[20];
  const float* bih     = (const float*)d_in[21];
  const float* bhh     = (const float*)d_in[22];
  const float* r_w0    = (const float*)d_in[23];
  const float* r_b0    = (const float*)d_in[24];
  const float* r_w1    = (const float*)d_in[25];
  const float* r_b1    = (const float*)d_in[26];
  const float* r_w2    = (const float*)d_in[27];
  const float* r_b2    = (const float*)d_in[28];
  const float* c0      = (const float*)d_in[29];
  const int*   grids   = (const int*)d_in[30];
  const int*   edges   = (const int*)d_in[31];

  float* out = (float*)d_out;
  const int iters = out_size / (BN * 9);   // = 4

  float* ws   = (float*)d_ws;
  float* H    = ws;                 // BN*96
  float* c    = H    + (size_t)BN * 96;
  float* Xg   = c    + (size_t)BN * 96;
  float* BufA = Xg   + (size_t)BN * 96;
  float* BufB = BufA + (size_t)BN * 96;
  float* BufS = BufB + (size_t)BN * 96;
  float* gates= BufS + (size_t)BN * 96;    // BN*384
  float* emb  = gates;                     // reuse gates region (BN*16) before loop

  // ---- prologue ----
  embed_lookup_k<<<(BN * 16 + 255) / 256, 256, 0, stream>>>(embed, grids, emb);
  // in-MLP: emb(16) -> 96 -> 96 -> 96 (last no relu) => X stored in H
  run_gemm(stream, emb, 16,  in_w0, 16, in_b0, 1.f, nullptr, 0, BufA, 96, BN, 96, 16, 1);
  run_gemm(stream, BufA, 96, in_w1, 96, in_b1, 1.f, nullptr, 0, BufB, 96, BN, 96, 96, 1);
  run_gemm(stream, BufB, 96, in_w2, 96, in_b2, 1.f, nullptr, 0, H,    96, BN, 96, 96, 0);
  // Xg = X @ g_w0[:, :96]^T + g_b0   (iteration-invariant)
  run_gemm(stream, H, 96, g_w0, 192, g_b0, 1.f, nullptr, 0, Xg, 96, BN, 96, 96, 0);
  // c = c0 (d2d copy; can't mutate the input in place)
  hipMemcpyAsync(c, c0, (size_t)BN * 96 * sizeof(float), hipMemcpyDeviceToDevice, stream);

  for (int it = 0; it < iters; ++it) {
    // A_s = H @ f_w0[:, :96]^T ; A_n = H @ f_w0[:, 96:]^T   (bias added in edge kernel)
    run_gemm(stream, H, 96, f_w0,      192, nullptr, 0.f, nullptr, 0, BufA, 96, BN, 96, 96, 0);
    run_gemm(stream, H, 96, f_w0 + 96, 192, nullptr, 0.f, nullptr, 0, BufB, 96, BN, 96, 96, 0);
    // S = sum_j relu(W1 relu(A_s + A_n[nbr] + b0) + b1)
    edge_msg_k<<<BN / 4, 192, 0, stream>>>(BufA, BufB, f_w1, f_b0, f_b1, edges, BufS);
    // M = S @ f_w2^T + 20*f_b2
    run_gemm(stream, BufS, 96, f_w2, 96, f_b2, (float)KNB, nullptr, 0, BufA, 96, BN, 96, 96, 0);
    // g-MLP: z1 = relu(M @ g_w0[:,96:]^T + Xg); z2 = relu(z1 @ g_w1^T + g_b1); gin = z2 @ g_w2^T + g_b2
    run_gemm(stream, BufA, 96, g_w0 + 96, 192, nullptr, 0.f, Xg, 96, BufB, 96, BN, 96, 96, 1);
    run_gemm(stream, BufB, 96, g_w1, 96, g_b1, 1.f, nullptr, 0, BufS, 96, BN, 96, 96, 1);
    run_gemm(stream, BufS, 96, g_w2, 96, g_b2, 1.f, nullptr, 0, BufB, 96, BN, 96, 96, 0);
    // gates = gin @ wih^T + bih + h @ whh^T + bhh
    run_gemm(stream, BufB, 96, wih, 96, bih, 1.f, nullptr, 0, gates, 384, BN, 384, 96, 0);
    run_gemm(stream, H,    96, whh, 96, bhh, 1.f, gates, 384, gates, 384, BN, 384, 96, 0);
    // LSTM cell: updates c and H(=h)
    lstm_k<<<(BN * 96 + 255) / 256, 256, 0, stream>>>(gates, c, H);
    // r-MLP: H -> 96 -> 96 -> 9, write f32 output slice
    run_gemm(stream, H,    96, r_w0, 96, r_b0, 1.f, nullptr, 0, BufA, 96, BN, 96, 96, 1);
    run_gemm(stream, BufA, 96, r_w1, 96, r_b1, 1.f, nullptr, 0, BufB, 96, BN, 96, 96, 1);
    run_gemm(stream, BufB, 96, r_w2, 96, r_b2, 1.f, nullptr, 0,
             out + (size_t)it * BN * 9, 9, BN, 9, 96, 0);
  }
}

// Round 3
// 1311.245 us; speedup vs baseline: 2.0949x; 2.0949x over previous
//
#include <hip/hip_runtime.h>
#include <hip/hip_bf16.h>

typedef __hip_bfloat16 bf16;
typedef __attribute__((ext_vector_type(8))) short short8;
typedef __attribute__((ext_vector_type(8))) __bf16 bf16x8;
typedef __attribute__((ext_vector_type(4))) float f32x4;

#define BN 20736      // 256*81
#define NNODE 81
#define HID 96
#define KNB 20

__device__ inline float bf2f(short s) {
  union { unsigned u; float f; } x; x.u = ((unsigned)(unsigned short)s) << 16; return x.f;
}
__device__ inline short f2bf(float f) {
  __hip_bfloat16 h = __float2bfloat16(f);
  return *reinterpret_cast<short*>(&h);
}

// ---------------- embed lookup ----------------
__global__ __launch_bounds__(256) void embed_lookup_k(const float* __restrict__ embed,
                                                      const int* __restrict__ grids,
                                                      float* __restrict__ emb) {
  int idx = blockIdx.x * 256 + threadIdx.x;
  if (idx >= BN * 16) return;
  int r = idx >> 4, k = idx & 15;
  emb[idx] = embed[grids[r] * 16 + k];
}

// ---------------- f32 -> bf16 convert ----------------
__global__ __launch_bounds__(256) void cvt_f32_bf16_k(const float* __restrict__ in,
                                                      bf16* __restrict__ out, int n) {
  int idx = blockIdx.x * 256 + threadIdx.x;
  if (idx < n) out[idx] = __float2bfloat16(in[idx]);
}

// ---------------- generic f32 GEMM: C = act(A @ W^T + bscale*bias + D) ----------------
// If Cb non-null, write bf16 to Cb instead of f32 to C.
__global__ __launch_bounds__(256) void gemm_k(
    const float* __restrict__ A, int lda,
    const float* __restrict__ W, int ldw,
    const float* __restrict__ bias, float bscale,
    const float* __restrict__ D, int ldd,
    float* __restrict__ C, bf16* __restrict__ Cb, int ldc,
    int M, int N, int K, int act)
{
  __shared__ float As[16][68];
  __shared__ float Ws[16][68];
  const int t = threadIdx.x;
  const int tx = t & 15, ty = t >> 4;
  const int m0 = blockIdx.x * 64, n0 = blockIdx.y * 64;
  float acc[4][4] = {};
  const int kload = t & 15, mload = t >> 4;
  for (int k0 = 0; k0 < K; k0 += 16) {
    #pragma unroll
    for (int p = 0; p < 4; ++p) {
      int mm = mload + p * 16;
      int gm = m0 + mm, gk = k0 + kload;
      As[kload][mm] = (gm < M && gk < K) ? A[(size_t)gm * lda + gk] : 0.f;
      int gn = n0 + mm;
      Ws[kload][mm] = (gn < N && gk < K) ? W[(size_t)gn * ldw + gk] : 0.f;
    }
    __syncthreads();
    #pragma unroll
    for (int k = 0; k < 16; ++k) {
      float4 a4 = *(const float4*)&As[k][4 * ty];
      float4 w4 = *(const float4*)&Ws[k][4 * tx];
      float av[4] = {a4.x, a4.y, a4.z, a4.w};
      float wv[4] = {w4.x, w4.y, w4.z, w4.w};
      #pragma unroll
      for (int im = 0; im < 4; ++im)
        #pragma unroll
        for (int jn = 0; jn < 4; ++jn)
          acc[im][jn] += av[im] * wv[jn];
    }
    __syncthreads();
  }
  #pragma unroll
  for (int im = 0; im < 4; ++im) {
    int m = m0 + 4 * ty + im;
    if (m >= M) continue;
    #pragma unroll
    for (int jn = 0; jn < 4; ++jn) {
      int n = n0 + 4 * tx + jn;
      if (n >= N) continue;
      float v = acc[im][jn];
      if (bias) v += bscale * bias[n];
      if (D) v += D[(size_t)m * ldd + n];
      if (act == 1) v = fmaxf(v, 0.f);
      if (Cb) Cb[(size_t)m * ldc + n] = __float2bfloat16(v);
      else    C[(size_t)m * ldc + n] = v;
    }
  }
}

// ---------------- MFMA edge-message kernel ----------------
// Per block (192 thr = 3 waves): 4 node-rows, Z1[80][96] = relu(As[row] + An[nbr]),
// then S[node] = sum_over_20_edges relu(Z1 @ W1^T + b1).  One barrier total.
#define ZPAD 112   // padded stride (shorts); 112*2 = 224 B = 14*16 -> 16B-aligned rows
__global__ __launch_bounds__(192) void edge_mfma_k(
    const bf16* __restrict__ Asb,   // BN x 96 (b0 folded in)
    const bf16* __restrict__ Anb,   // BN x 96
    const bf16* __restrict__ w1bf,  // 96 x 96
    const float* __restrict__ b1,   // 96
    const int* __restrict__ edges,  // 81 x 20
    float* __restrict__ S)          // BN x 96
{
  __shared__ short w1s[96 * ZPAD];
  __shared__ short z1s[80 * ZPAD];
  const int t = threadIdx.x;
  const int row0 = blockIdx.x * 4;

  // stage W1 (bf16): 96 rows x 12 16B-chunks = 1152, 6 per thread
  for (int cc = t; cc < 96 * 12; cc += 192) {
    int n = cc / 12, c8 = cc - n * 12;
    *(short8*)&w1s[n * ZPAD + c8 * 8] = *(const short8*)&w1bf[n * 96 + c8 * 8];
  }
  // build Z1: 80 rows x 12 chunks = 960, 5 per thread
  for (int cc = t; cc < 80 * 12; cc += 192) {
    int row = cc / 12, c8 = cc - row * 12;
    int p = row / 20, j = row - p * 20;
    int gr = row0 + p;
    int b = gr / NNODE, i = gr - b * NNODE;
    int e = edges[i * KNB + j];
    short8 a8 = *(const short8*)&Asb[(size_t)gr * 96 + c8 * 8];
    short8 n8 = *(const short8*)&Anb[((size_t)b * NNODE + e) * 96 + c8 * 8];
    short8 z;
    #pragma unroll
    for (int q = 0; q < 8; ++q)
      z[q] = f2bf(fmaxf(bf2f(a8[q]) + bf2f(n8[q]), 0.f));
    *(short8*)&z1s[row * ZPAD + c8 * 8] = z;
  }
  __syncthreads();

  const int w = t >> 6, lane = t & 63;
  const int lr = lane & 15, lq = lane >> 4;
  // wave w owns col-tiles n0 = 32w and 32w+16
  f32x4 acc[5][2];
  #pragma unroll
  for (int mt = 0; mt < 5; ++mt)
    #pragma unroll
    for (int tt = 0; tt < 2; ++tt)
      acc[mt][tt] = (f32x4){0.f, 0.f, 0.f, 0.f};

  #pragma unroll
  for (int ks = 0; ks < 3; ++ks) {
    const int koff = ks * 32 + lq * 8;
    bf16x8 bf0 = __builtin_bit_cast(bf16x8, *(const short8*)&w1s[(w * 32 + lr) * ZPAD + koff]);
    bf16x8 bf1 = __builtin_bit_cast(bf16x8, *(const short8*)&w1s[(w * 32 + 16 + lr) * ZPAD + koff]);
    #pragma unroll
    for (int mt = 0; mt < 5; ++mt) {
      bf16x8 af = __builtin_bit_cast(bf16x8, *(const short8*)&z1s[(mt * 16 + lr) * ZPAD + koff]);
      acc[mt][0] = __builtin_amdgcn_mfma_f32_16x16x32_bf16(af, bf0, acc[mt][0], 0, 0, 0);
      acc[mt][1] = __builtin_amdgcn_mfma_f32_16x16x32_bf16(af, bf1, acc[mt][1], 0, 0, 0);
    }
  }

  // epilogue: bias + relu, predicated per-node accumulation (static indices only)
  float biasv[2] = { b1[w * 32 + lr], b1[w * 32 + 16 + lr] };
  float nodeacc[4][2];
  #pragma unroll
  for (int pp = 0; pp < 4; ++pp) { nodeacc[pp][0] = 0.f; nodeacc[pp][1] = 0.f; }
  #pragma unroll
  for (int mt = 0; mt < 5; ++mt)
    #pragma unroll
    for (int tt = 0; tt < 2; ++tt)
      #pragma unroll
      for (int r = 0; r < 4; ++r) {
        int row = mt * 16 + lq * 4 + r;   // 0..79 (4-row group never crosses node bdry)
        int p = row / 20;
        float v = fmaxf(acc[mt][tt][r] + biasv[tt], 0.f);
        #pragma unroll
        for (int pp = 0; pp < 4; ++pp)
          nodeacc[pp][tt] += (p == pp) ? v : 0.f;
      }
  #pragma unroll
  for (int pp = 0; pp < 4; ++pp)
    #pragma unroll
    for (int tt = 0; tt < 2; ++tt) {
      float v = nodeacc[pp][tt];
      v += __shfl_xor(v, 16, 64);
      v += __shfl_xor(v, 32, 64);
      if (lq == 0)
        S[(size_t)(row0 + pp) * 96 + w * 32 + tt * 16 + lr] = v;
    }
}

// ---------------- LSTM cell elementwise ----------------
__global__ __launch_bounds__(256) void lstm_k(const float* __restrict__ gates,
                                              float* __restrict__ c, float* __restrict__ H) {
  int idx = blockIdx.x * 256 + threadIdx.x;
  if (idx >= BN * HID) return;
  int r = idx / HID, k = idx - r * HID;
  const float* g = gates + (size_t)r * 384;
  float gi = g[k], gf = g[96 + k], gg = g[192 + k], go = g[288 + k];
  float si = 1.f / (1.f + expf(-gi));
  float sf = 1.f / (1.f + expf(-gf));
  float so = 1.f / (1.f + expf(-go));
  float tg = tanhf(gg);
  float cn = sf * c[idx] + si * tg;
  c[idx] = cn;
  H[idx] = so * tanhf(cn);
}

// ---------------- host side ----------------
static inline void run_gemm(hipStream_t s, const float* A, int lda, const float* W, int ldw,
                            const float* bias, float bscale, const float* D, int ldd,
                            float* C, bf16* Cb, int ldc, int M, int N, int K, int act) {
  dim3 grid((M + 63) / 64, (N + 63) / 64);
  gemm_k<<<grid, 256, 0, s>>>(A, lda, W, ldw, bias, bscale, D, ldd, C, Cb, ldc, M, N, K, act);
}

extern "C" void kernel_launch(void* const* d_in, const int* in_sizes, int n_in,
                              void* d_out, int out_size, void* d_ws, size_t ws_size,
                              hipStream_t stream) {
  const float* embed   = (const float*)d_in[0];
  const float* in_w0   = (const float*)d_in[1];
  const float* in_b0   = (const float*)d_in[2];
  const float* in_w1   = (const float*)d_in[3];
  const float* in_b1   = (const float*)d_in[4];
  const float* in_w2   = (const float*)d_in[5];
  const float* in_b2   = (const float*)d_in[6];
  const float* f_w0    = (const float*)d_in[7];
  const float* f_b0    = (const float*)d_in[8];
  const float* f_w1    = (const float*)d_in[9];
  const float* f_b1    = (const float*)d_in[10];
  const float* f_w2    = (const float*)d_in[11];
  const float* f_b2    = (const float*)d_in[12];
  const float* g_w0    = (const float*)d_in[13];
  const float* g_b0    = (const float*)d_in[14];
  const float* g_w1    = (const float*)d_in[15];
  const float* g_b1    = (const float*)d_in[16];
  const float* g_w2    = (const float*)d_in[17];
  const float* g_b2    = (const float*)d_in[18];
  const float* wih     = (const float*)d_in[19];
  const float* whh     = (const float*)d_in[20];
  const float* bih     = (const float*)d_in[21];
  const float* bhh     = (const float*)d_in[22];
  const float* r_w0    = (const float*)d_in[23];
  const float* r_b0    = (const float*)d_in[24];
  const float* r_w1    = (const float*)d_in[25];
  const float* r_b1    = (const float*)d_in[26];
  const float* r_w2    = (const float*)d_in[27];
  const float* r_b2    = (const float*)d_in[28];
  const float* c0      = (const float*)d_in[29];
  const int*   grids   = (const int*)d_in[30];
  const int*   edges   = (const int*)d_in[31];

  float* out = (float*)d_out;
  const int iters = out_size / (BN * 9);   // = 4

  float* ws   = (float*)d_ws;
  float* H    = ws;                        // BN*96 f32 (persistent)
  float* c    = H    + (size_t)BN * 96;
  float* Xg   = c    + (size_t)BN * 96;
  float* BufA = Xg   + (size_t)BN * 96;
  float* BufB = BufA + (size_t)BN * 96;
  float* BufS = BufB + (size_t)BN * 96;
  float* gates= BufS + (size_t)BN * 96;    // BN*384
  bf16*  w1bf = (bf16*)(gates + (size_t)BN * 384);   // 96*96 bf16 (persistent)
  float* emb  = gates;                     // overlay: BN*16 used only in prologue
  bf16*  As_bf = (bf16*)BufA;              // overlay: BN*96 bf16, dead after edge kernel
  bf16*  An_bf = As_bf + (size_t)BN * 96;

  // ---- prologue ----
  embed_lookup_k<<<(BN * 16 + 255) / 256, 256, 0, stream>>>(embed, grids, emb);
  run_gemm(stream, emb, 16,  in_w0, 16, in_b0, 1.f, nullptr, 0, BufA, nullptr, 96, BN, 96, 16, 1);
  run_gemm(stream, BufA, 96, in_w1, 96, in_b1, 1.f, nullptr, 0, BufB, nullptr, 96, BN, 96, 96, 1);
  run_gemm(stream, BufB, 96, in_w2, 96, in_b2, 1.f, nullptr, 0, H,    nullptr, 96, BN, 96, 96, 0);
  run_gemm(stream, H, 96, g_w0, 192, g_b0, 1.f, nullptr, 0, Xg, nullptr, 96, BN, 96, 96, 0);
  cvt_f32_bf16_k<<<(96 * 96 + 255) / 256, 256, 0, stream>>>(f_w1, w1bf, 96 * 96);
  hipMemcpyAsync(c, c0, (size_t)BN * 96 * sizeof(float), hipMemcpyDeviceToDevice, stream);

  for (int it = 0; it < iters; ++it) {
    // As = H @ f_w0[:, :96]^T + b0 (bf16 out); An = H @ f_w0[:, 96:]^T (bf16 out)
    run_gemm(stream, H, 96, f_w0,      192, f_b0, 1.f, nullptr, 0, nullptr, As_bf, 96, BN, 96, 96, 0);
    run_gemm(stream, H, 96, f_w0 + 96, 192, nullptr, 0.f, nullptr, 0, nullptr, An_bf, 96, BN, 96, 96, 0);
    // S = sum_j relu(W1 relu(As + An[nbr]) + b1)   [MFMA]
    edge_mfma_k<<<BN / 4, 192, 0, stream>>>(As_bf, An_bf, w1bf, f_b1, edges, BufS);
    // M = S @ f_w2^T + 20*f_b2
    run_gemm(stream, BufS, 96, f_w2, 96, f_b2, (float)KNB, nullptr, 0, BufA, nullptr, 96, BN, 96, 96, 0);
    // g-MLP
    run_gemm(stream, BufA, 96, g_w0 + 96, 192, nullptr, 0.f, Xg, 96, BufB, nullptr, 96, BN, 96, 96, 1);
    run_gemm(stream, BufB, 96, g_w1, 96, g_b1, 1.f, nullptr, 0, BufS, nullptr, 96, BN, 96, 96, 1);
    run_gemm(stream, BufS, 96, g_w2, 96, g_b2, 1.f, nullptr, 0, BufB, nullptr, 96, BN, 96, 96, 0);
    // gates = gin @ wih^T + bih + h @ whh^T + bhh
    run_gemm(stream, BufB, 96, wih, 96, bih, 1.f, nullptr, 0, gates, nullptr, 384, BN, 384, 96, 0);
    run_gemm(stream, H,    96, whh, 96, bhh, 1.f, gates, 384, gates, nullptr, 384, BN, 384, 96, 0);
    lstm_k<<<(BN * 96 + 255) / 256, 256, 0, stream>>>(gates, c, H);
    // r-MLP
    run_gemm(stream, H,    96, r_w0, 96, r_b0, 1.f, nullptr, 0, BufA, nullptr, 96, BN, 96, 96, 1);
    run_gemm(stream, BufA, 96, r_w1, 96, r_b1, 1.f, nullptr, 0, BufB, nullptr, 96, BN, 96, 96, 1);
    run_gemm(stream, BufB, 96, r_w2, 96, r_b2, 1.f, nullptr, 0,
             out + (size_t)it * BN * 9, nullptr, 9, BN, 9, 96, 0);
  }
}

// Round 4
// 808.944 us; speedup vs baseline: 3.3958x; 1.6209x over previous
//
#include <hip/hip_runtime.h>
#include <hip/hip_bf16.h>

typedef __hip_bfloat16 bf16;
typedef __attribute__((ext_vector_type(8))) short short8;
typedef __attribute__((ext_vector_type(8))) __bf16 bf16x8;
typedef __attribute__((ext_vector_type(4))) float f32x4;

#define BN 20736      // 256*81
#define NNODE 81
#define HID 96
#define KNB 20

__device__ inline float bf2f(short s) {
  union { unsigned u; float f; } x; x.u = ((unsigned)(unsigned short)s) << 16; return x.f;
}
__device__ inline short f2bf(float f) {
  __hip_bfloat16 h = __float2bfloat16(f);
  return *reinterpret_cast<short*>(&h);
}
__device__ inline bf16x8 cvt_frag(float4 a, float4 b) {
  short8 s;
  s[0] = f2bf(a.x); s[1] = f2bf(a.y); s[2] = f2bf(a.z); s[3] = f2bf(a.w);
  s[4] = f2bf(b.x); s[5] = f2bf(b.y); s[6] = f2bf(b.z); s[7] = f2bf(b.w);
  return __builtin_bit_cast(bf16x8, s);
}

// ---------------- prologue pad kernels ----------------
__global__ __launch_bounds__(256) void pad_emb_k(const float* __restrict__ embed,
                                                 const int* __restrict__ grids,
                                                 float* __restrict__ emb32) {
  int idx = blockIdx.x * 256 + threadIdx.x;
  if (idx >= BN * 32) return;
  int r = idx >> 5, k = idx & 31;
  emb32[idx] = (k < 16) ? embed[grids[r] * 16 + k] : 0.f;
}
__global__ __launch_bounds__(256) void pad_w0_k(const float* __restrict__ w,
                                                float* __restrict__ wp) {
  int idx = blockIdx.x * 256 + threadIdx.x;
  if (idx >= 96 * 32) return;
  int r = idx >> 5, k = idx & 31;
  wp[idx] = (k < 16) ? w[r * 16 + k] : 0.f;
}
__global__ __launch_bounds__(256) void cvt_f32_bf16_k(const float* __restrict__ in,
                                                      bf16* __restrict__ out, int n) {
  int idx = blockIdx.x * 256 + threadIdx.x;
  if (idx < n) out[idx] = __float2bfloat16(in[idx]);
}

// ---------------- LDS-free MFMA GEMM ----------------
// C[BN,N] = act(A[BN,K] @ W[N,K]^T + bscale*bias + D); K = 32*KS; N <= 16*NT.
// Block = 128 thr = 2 waves; wave owns 16 rows; W-fragments live in VGPRs.
template<int NT, int KS>
__global__ __launch_bounds__(128) void mfma_gemm_k(
    const float* __restrict__ A, int lda,
    const float* __restrict__ W, int ldw,
    const float* __restrict__ bias, float bscale,
    const float* __restrict__ D, int ldd,
    float* __restrict__ Cf, bf16* __restrict__ Cb, int ldc,
    int N, int act)
{
  const int t = threadIdx.x;
  const int w = t >> 6, lane = t & 63;
  const int lr = lane & 15, lq = lane >> 4;
  const int m0 = blockIdx.x * 32 + w * 16;

  bf16x8 wf[NT][KS];
  #pragma unroll
  for (int nt = 0; nt < NT; ++nt) {
    int n = nt * 16 + lr;
    bool nok = n < N;
    #pragma unroll
    for (int ks = 0; ks < KS; ++ks) {
      float4 lo = make_float4(0.f, 0.f, 0.f, 0.f), hi = lo;
      if (nok) {
        lo = *(const float4*)&W[(size_t)n * ldw + ks * 32 + lq * 8];
        hi = *(const float4*)&W[(size_t)n * ldw + ks * 32 + lq * 8 + 4];
      }
      wf[nt][ks] = cvt_frag(lo, hi);
    }
  }
  f32x4 acc[NT];
  #pragma unroll
  for (int nt = 0; nt < NT; ++nt) acc[nt] = (f32x4){0.f, 0.f, 0.f, 0.f};

  #pragma unroll
  for (int ks = 0; ks < KS; ++ks) {
    float4 lo = *(const float4*)&A[(size_t)(m0 + lr) * lda + ks * 32 + lq * 8];
    float4 hi = *(const float4*)&A[(size_t)(m0 + lr) * lda + ks * 32 + lq * 8 + 4];
    bf16x8 af = cvt_frag(lo, hi);
    #pragma unroll
    for (int nt = 0; nt < NT; ++nt)
      acc[nt] = __builtin_amdgcn_mfma_f32_16x16x32_bf16(af, wf[nt][ks], acc[nt], 0, 0, 0);
  }

  #pragma unroll
  for (int nt = 0; nt < NT; ++nt) {
    int n = nt * 16 + lr;
    if (n >= N) continue;
    float bv = bias ? bscale * bias[n] : 0.f;
    #pragma unroll
    for (int r = 0; r < 4; ++r) {
      int m = m0 + lq * 4 + r;
      float v = acc[nt][r] + bv;
      if (D) v += D[(size_t)m * ldd + n];
      if (act) v = fmaxf(v, 0.f);
      if (Cf) Cf[(size_t)m * ldc + n] = v;
      if (Cb) Cb[(size_t)m * ldc + n] = __float2bfloat16(v);
    }
  }
}

// ---------------- fused gates + LSTM kernel ----------------
// gates = gin @ wih^T + bih + h @ whh^T + bhh; LSTM cell in-register; writes c, H.
#define WLD 104   // padded LDS stride in shorts (208 B -> ~2-way, free)
__global__ __launch_bounds__(256) void lstm_fused_k(
    const float* __restrict__ gin,   // BN x 96
    const float* __restrict__ wih,   // 384 x 96
    const float* __restrict__ whh,   // 384 x 96
    const float* __restrict__ bih, const float* __restrict__ bhh,
    float* __restrict__ c, float* __restrict__ H)
{
  __shared__ short ws_[192 * WLD];
  const int t = threadIdx.x;
  const int w = t >> 6, lane = t & 63;
  const int lr = lane & 15, lq = lane >> 4;
  const int m0 = blockIdx.x * 64 + w * 16;

  f32x4 acc[24];
  #pragma unroll
  for (int i = 0; i < 24; ++i) acc[i] = (f32x4){0.f, 0.f, 0.f, 0.f};

  for (int s = 0; s < 4; ++s) {
    const float* Wsrc = (s < 2 ? wih : whh) + (size_t)(s & 1) * 192 * 96;
    const float* Asrc = (s < 2) ? gin : H;
    if (s) __syncthreads();            // all waves done reading LDS before restage
    for (int i = t; i < 192 * 24; i += 256) {
      int row = i / 24, c4 = i - row * 24;
      float4 v = *(const float4*)&Wsrc[(size_t)row * 96 + c4 * 4];
      short4 sv;
      sv.x = f2bf(v.x); sv.y = f2bf(v.y); sv.z = f2bf(v.z); sv.w = f2bf(v.w);
      *(short4*)&ws_[row * WLD + c4 * 4] = sv;
    }
    __syncthreads();
    #pragma unroll
    for (int ks = 0; ks < 3; ++ks) {
      float4 lo = *(const float4*)&Asrc[(size_t)(m0 + lr) * 96 + ks * 32 + lq * 8];
      float4 hi = *(const float4*)&Asrc[(size_t)(m0 + lr) * 96 + ks * 32 + lq * 8 + 4];
      bf16x8 af = cvt_frag(lo, hi);
      #pragma unroll
      for (int nt = 0; nt < 12; ++nt) {
        bf16x8 bf = __builtin_bit_cast(bf16x8,
            *(const short8*)&ws_[(nt * 16 + lr) * WLD + ks * 32 + lq * 8]);
        int ntg = (s & 1) * 12 + nt;
        acc[ntg] = __builtin_amdgcn_mfma_f32_16x16x32_bf16(af, bf, acc[ntg], 0, 0, 0);
      }
    }
  }

  float bv[24];
  #pragma unroll
  for (int nt = 0; nt < 24; ++nt) { int n = nt * 16 + lr; bv[nt] = bih[n] + bhh[n]; }
  #pragma unroll
  for (int knt = 0; knt < 6; ++knt) {
    #pragma unroll
    for (int r = 0; r < 4; ++r) {
      int m = m0 + lq * 4 + r;
      int kcol = knt * 16 + lr;
      float gi = acc[knt][r]      + bv[knt];
      float gf = acc[knt + 6][r]  + bv[knt + 6];
      float gg = acc[knt + 12][r] + bv[knt + 12];
      float go = acc[knt + 18][r] + bv[knt + 18];
      float si = 1.f / (1.f + expf(-gi));
      float sf = 1.f / (1.f + expf(-gf));
      float so = 1.f / (1.f + expf(-go));
      float tg = tanhf(gg);
      size_t idx = (size_t)m * 96 + kcol;
      float cn = sf * c[idx] + si * tg;
      c[idx] = cn;
      H[idx] = so * tanhf(cn);
    }
  }
}

// ---------------- MFMA edge-message kernel (unchanged from R3) ----------------
#define ZPAD 112
__global__ __launch_bounds__(192) void edge_mfma_k(
    const bf16* __restrict__ Asb, const bf16* __restrict__ Anb,
    const bf16* __restrict__ w1bf, const float* __restrict__ b1,
    const int* __restrict__ edges, float* __restrict__ S)
{
  __shared__ short w1s[96 * ZPAD];
  __shared__ short z1s[80 * ZPAD];
  const int t = threadIdx.x;
  const int row0 = blockIdx.x * 4;

  for (int cc = t; cc < 96 * 12; cc += 192) {
    int n = cc / 12, c8 = cc - n * 12;
    *(short8*)&w1s[n * ZPAD + c8 * 8] = *(const short8*)&w1bf[n * 96 + c8 * 8];
  }
  for (int cc = t; cc < 80 * 12; cc += 192) {
    int row = cc / 12, c8 = cc - row * 12;
    int p = row / 20, j = row - p * 20;
    int gr = row0 + p;
    int b = gr / NNODE, i = gr - b * NNODE;
    int e = edges[i * KNB + j];
    short8 a8 = *(const short8*)&Asb[(size_t)gr * 96 + c8 * 8];
    short8 n8 = *(const short8*)&Anb[((size_t)b * NNODE + e) * 96 + c8 * 8];
    short8 z;
    #pragma unroll
    for (int q = 0; q < 8; ++q)
      z[q] = f2bf(fmaxf(bf2f(a8[q]) + bf2f(n8[q]), 0.f));
    *(short8*)&z1s[row * ZPAD + c8 * 8] = z;
  }
  __syncthreads();

  const int w = t >> 6, lane = t & 63;
  const int lr = lane & 15, lq = lane >> 4;
  f32x4 acc[5][2];
  #pragma unroll
  for (int mt = 0; mt < 5; ++mt)
    #pragma unroll
    for (int tt = 0; tt < 2; ++tt)
      acc[mt][tt] = (f32x4){0.f, 0.f, 0.f, 0.f};

  #pragma unroll
  for (int ks = 0; ks < 3; ++ks) {
    const int koff = ks * 32 + lq * 8;
    bf16x8 bf0 = __builtin_bit_cast(bf16x8, *(const short8*)&w1s[(w * 32 + lr) * ZPAD + koff]);
    bf16x8 bf1 = __builtin_bit_cast(bf16x8, *(const short8*)&w1s[(w * 32 + 16 + lr) * ZPAD + koff]);
    #pragma unroll
    for (int mt = 0; mt < 5; ++mt) {
      bf16x8 af = __builtin_bit_cast(bf16x8, *(const short8*)&z1s[(mt * 16 + lr) * ZPAD + koff]);
      acc[mt][0] = __builtin_amdgcn_mfma_f32_16x16x32_bf16(af, bf0, acc[mt][0], 0, 0, 0);
      acc[mt][1] = __builtin_amdgcn_mfma_f32_16x16x32_bf16(af, bf1, acc[mt][1], 0, 0, 0);
    }
  }

  float biasv[2] = { b1[w * 32 + lr], b1[w * 32 + 16 + lr] };
  float nodeacc[4][2];
  #pragma unroll
  for (int pp = 0; pp < 4; ++pp) { nodeacc[pp][0] = 0.f; nodeacc[pp][1] = 0.f; }
  #pragma unroll
  for (int mt = 0; mt < 5; ++mt)
    #pragma unroll
    for (int tt = 0; tt < 2; ++tt)
      #pragma unroll
      for (int r = 0; r < 4; ++r) {
        int row = mt * 16 + lq * 4 + r;
        int p = row / 20;
        float v = fmaxf(acc[mt][tt][r] + biasv[tt], 0.f);
        #pragma unroll
        for (int pp = 0; pp < 4; ++pp)
          nodeacc[pp][tt] += (p == pp) ? v : 0.f;
      }
  #pragma unroll
  for (int pp = 0; pp < 4; ++pp)
    #pragma unroll
    for (int tt = 0; tt < 2; ++tt) {
      float v = nodeacc[pp][tt];
      v += __shfl_xor(v, 16, 64);
      v += __shfl_xor(v, 32, 64);
      if (lq == 0)
        S[(size_t)(row0 + pp) * 96 + w * 32 + tt * 16 + lr] = v;
    }
}

// ---------------- host side ----------------
typedef const float* cfp;
static inline void mg(hipStream_t s, int NT, int KS, cfp A, int lda, cfp W, int ldw,
                      cfp bias, float bsc, cfp D, int ldd,
                      float* Cf, bf16* Cb, int ldc, int N, int act) {
  dim3 g(BN / 32);
  if (NT == 6 && KS == 3)
    mfma_gemm_k<6, 3><<<g, 128, 0, s>>>(A, lda, W, ldw, bias, bsc, D, ldd, Cf, Cb, ldc, N, act);
  else if (NT == 6 && KS == 1)
    mfma_gemm_k<6, 1><<<g, 128, 0, s>>>(A, lda, W, ldw, bias, bsc, D, ldd, Cf, Cb, ldc, N, act);
  else
    mfma_gemm_k<1, 3><<<g, 128, 0, s>>>(A, lda, W, ldw, bias, bsc, D, ldd, Cf, Cb, ldc, N, act);
}

extern "C" void kernel_launch(void* const* d_in, const int* in_sizes, int n_in,
                              void* d_out, int out_size, void* d_ws, size_t ws_size,
                              hipStream_t stream) {
  const float* embed   = (const float*)d_in[0];
  const float* in_w0   = (const float*)d_in[1];
  const float* in_b0   = (const float*)d_in[2];
  const float* in_w1   = (const float*)d_in[3];
  const float* in_b1   = (const float*)d_in[4];
  const float* in_w2   = (const float*)d_in[5];
  const float* in_b2   = (const float*)d_in[6];
  const float* f_w0    = (const float*)d_in[7];
  const float* f_b0    = (const float*)d_in[8];
  const float* f_w1    = (const float*)d_in[9];
  const float* f_b1    = (const float*)d_in[10];
  const float* f_w2    = (const float*)d_in[11];
  const float* f_b2    = (const float*)d_in[12];
  const float* g_w0    = (const float*)d_in[13];
  const float* g_b0    = (const float*)d_in[14];
  const float* g_w1    = (const float*)d_in[15];
  const float* g_b1    = (const float*)d_in[16];
  const float* g_w2    = (const float*)d_in[17];
  const float* g_b2    = (const float*)d_in[18];
  const float* wih     = (const float*)d_in[19];
  const float* whh     = (const float*)d_in[20];
  const float* bih     = (const float*)d_in[21];
  const float* bhh     = (const float*)d_in[22];
  const float* r_w0    = (const float*)d_in[23];
  const float* r_b0    = (const float*)d_in[24];
  const float* r_w1    = (const float*)d_in[25];
  const float* r_b1    = (const float*)d_in[26];
  const float* r_w2    = (const float*)d_in[27];
  const float* r_b2    = (const float*)d_in[28];
  const float* c0      = (const float*)d_in[29];
  const int*   grids   = (const int*)d_in[30];
  const int*   edges   = (const int*)d_in[31];

  float* out = (float*)d_out;
  const int iters = out_size / (BN * 9);   // = 4

  float* ws    = (float*)d_ws;
  float* H     = ws;                         // BN*96
  float* c     = H     + (size_t)BN * 96;
  float* Xg    = c     + (size_t)BN * 96;
  float* BufA  = Xg    + (size_t)BN * 96;
  float* BufB  = BufA  + (size_t)BN * 96;
  float* BufS  = BufB  + (size_t)BN * 96;
  bf16*  As_bf = (bf16*)(BufS + (size_t)BN * 96);   // BN*96 bf16
  bf16*  An_bf = As_bf + (size_t)BN * 96;           // BN*96 bf16
  float* emb32 = (float*)(An_bf + (size_t)BN * 96); // BN*32 f32
  float* w0p   = emb32 + (size_t)BN * 32;           // 96*32 f32
  bf16*  w1bf  = (bf16*)(w0p + 96 * 32);            // 96*96 bf16

  // ---- prologue ----
  pad_emb_k<<<(BN * 32 + 255) / 256, 256, 0, stream>>>(embed, grids, emb32);
  pad_w0_k<<<(96 * 32 + 255) / 256, 256, 0, stream>>>(in_w0, w0p);
  cvt_f32_bf16_k<<<(96 * 96 + 255) / 256, 256, 0, stream>>>(f_w1, w1bf, 96 * 96);
  mg(stream, 6, 1, emb32, 32, w0p, 32, in_b0, 1.f, nullptr, 0, BufA, nullptr, 96, 96, 1);
  mg(stream, 6, 3, BufA, 96, in_w1, 96, in_b1, 1.f, nullptr, 0, BufB, nullptr, 96, 96, 1);
  mg(stream, 6, 3, BufB, 96, in_w2, 96, in_b2, 1.f, nullptr, 0, H, nullptr, 96, 96, 0);
  mg(stream, 6, 3, H, 96, g_w0, 192, g_b0, 1.f, nullptr, 0, Xg, nullptr, 96, 96, 0);
  hipMemcpyAsync(c, c0, (size_t)BN * 96 * sizeof(float), hipMemcpyDeviceToDevice, stream);

  for (int it = 0; it < iters; ++it) {
    // As = H @ f_w0[:, :96]^T + b0 ; An = H @ f_w0[:, 96:]^T  (bf16 out)
    mg(stream, 6, 3, H, 96, f_w0,      192, f_b0, 1.f, nullptr, 0, nullptr, As_bf, 96, 96, 0);
    mg(stream, 6, 3, H, 96, f_w0 + 96, 192, nullptr, 0.f, nullptr, 0, nullptr, An_bf, 96, 96, 0);
    // S = sum_j relu(W1 relu(As + An[nbr]) + b1)
    edge_mfma_k<<<BN / 4, 192, 0, stream>>>(As_bf, An_bf, w1bf, f_b1, edges, BufS);
    // M = S @ f_w2^T + 20*f_b2
    mg(stream, 6, 3, BufS, 96, f_w2, 96, f_b2, (float)KNB, nullptr, 0, BufA, nullptr, 96, 96, 0);
    // g-MLP: z1 = relu(M @ g_w0[:,96:]^T + Xg); z2 = relu(z1 W1 + b); gin = z2 W2 + b
    mg(stream, 6, 3, BufA, 96, g_w0 + 96, 192, nullptr, 0.f, Xg, 96, BufB, nullptr, 96, 96, 1);
    mg(stream, 6, 3, BufB, 96, g_w1, 96, g_b1, 1.f, nullptr, 0, BufS, nullptr, 96, 96, 1);
    mg(stream, 6, 3, BufS, 96, g_w2, 96, g_b2, 1.f, nullptr, 0, BufA, nullptr, 96, 96, 0);
    // gates + LSTM fused (no gates buffer)
    lstm_fused_k<<<BN / 64, 256, 0, stream>>>(BufA, wih, whh, bih, bhh, c, H);
    // r-MLP
    mg(stream, 6, 3, H,    96, r_w0, 96, r_b0, 1.f, nullptr, 0, BufB, nullptr, 96, 96, 1);
    mg(stream, 6, 3, BufB, 96, r_w1, 96, r_b1, 1.f, nullptr, 0, BufS, nullptr, 96, 96, 1);
    mg(stream, 1, 3, BufS, 96, r_w2, 96, r_b2, 1.f, nullptr, 0,
       out + (size_t)it * BN * 9, nullptr, 9, 9, 0);
  }
}

// Round 5
// 486.102 us; speedup vs baseline: 5.6510x; 1.6641x over previous
//
#include <hip/hip_runtime.h>
#include <hip/hip_bf16.h>

typedef __hip_bfloat16 bf16;
typedef __attribute__((ext_vector_type(8))) short short8;
typedef __attribute__((ext_vector_type(8))) __bf16 bf16x8;
typedef __attribute__((ext_vector_type(4))) float f32x4;

#define BN 20736      // 256*81
#define NNODE 81
#define HID 96
#define KNB 20

__device__ inline float bf2f(short s) {
  union { unsigned u; float f; } x; x.u = ((unsigned)(unsigned short)s) << 16; return x.f;
}
__device__ inline short f2bf(float f) {
  __hip_bfloat16 h = __float2bfloat16(f);
  return *reinterpret_cast<short*>(&h);
}

// ================= prologue: convert/build all weights (one kernel) =================
__global__ __launch_bounds__(256) void prep_k(
    const float* in_w1, const float* in_w2, const float* f_w1, const float* f_w2,
    const float* g_w1, const float* g_w2, const float* r_w0, const float* r_w1,
    const float* r_w2, const float* wih, const float* whh, const float* g_w0,
    const float* f_w0, const float* in_w0, const float* f_b0,
    bf16* inw1b, bf16* inw2b, bf16* fw1b, bf16* fw2b,
    bf16* gw1b, bf16* gw2b, bf16* rw0b, bf16* rw1b,
    bf16* rw2b, bf16* wihb, bf16* whhb, bf16* gw0b,
    bf16* wfnb, bf16* w0pb, float* bias_fn)
{
  int idx = blockIdx.x * 256 + threadIdx.x;
  int y = blockIdx.y;
  const float* src = nullptr; bf16* dst = nullptr; int cnt = 0;
  switch (y) {
    case 0:  src = in_w1; dst = inw1b; cnt = 9216;  break;
    case 1:  src = in_w2; dst = inw2b; cnt = 9216;  break;
    case 2:  src = f_w1;  dst = fw1b;  cnt = 9216;  break;
    case 3:  src = f_w2;  dst = fw2b;  cnt = 9216;  break;
    case 4:  src = g_w1;  dst = gw1b;  cnt = 9216;  break;
    case 5:  src = g_w2;  dst = gw2b;  cnt = 9216;  break;
    case 6:  src = r_w0;  dst = rw0b;  cnt = 9216;  break;
    case 7:  src = r_w1;  dst = rw1b;  cnt = 9216;  break;
    case 8:  src = r_w2;  dst = rw2b;  cnt = 864;   break;
    case 9:  src = wih;   dst = wihb;  cnt = 36864; break;
    case 10: src = whh;   dst = whhb;  cnt = 36864; break;
    case 11: src = g_w0;  dst = gw0b;  cnt = 18432; break;
    case 12: { // wfn[192][96]: rows 0-95 = f_w0[n, 0:96]; rows 96-191 = f_w0[n-96, 96:192]
      if (idx < 18432) {
        int n = idx / 96, k = idx - n * 96;
        float v = (n < 96) ? f_w0[n * 192 + k] : f_w0[(n - 96) * 192 + 96 + k];
        wfnb[idx] = __float2bfloat16(v);
      }
      return;
    }
    case 13: { // w0p[96][32]: zero-padded in_w0 (96x16)
      if (idx < 3072) {
        int n = idx >> 5, k = idx & 31;
        w0pb[idx] = __float2bfloat16(k < 16 ? in_w0[n * 16 + k] : 0.f);
      }
      return;
    }
    default: { // bias_fn[192] = [f_b0, 0]
      if (idx < 192) bias_fn[idx] = (idx < 96) ? f_b0[idx] : 0.f;
      return;
    }
  }
  if (idx < cnt) dst[idx] = __float2bfloat16(src[idx]);
}

// ================= embed lookup -> padded bf16 [BN][32] =================
__global__ __launch_bounds__(256) void embed_k(const float* __restrict__ embed,
                                               const int* __restrict__ grids,
                                               bf16* __restrict__ emb) {
  int idx = blockIdx.x * 256 + threadIdx.x;
  if (idx >= BN * 32) return;
  int r = idx >> 5, k = idx & 31;
  emb[idx] = __float2bfloat16(k < 16 ? embed[grids[r] * 16 + k] : 0.f);
}

// ================= wave-autonomous bf16 MFMA GEMM =================
// Each wave: 16 rows x (NT*16) cols. gslot = rt*NGRP + cg. No LDS, no barriers.
// C = act(A[BN,K]@W[N,K]^T + bscale*bias + Dres)
template<int NT, int KS, int NGRP, bool F32OUT>
__global__ __launch_bounds__(256) void wgemm_k(
    const bf16* __restrict__ A, int lda,
    const bf16* __restrict__ W, int ldw,
    const float* __restrict__ bias, float bscale,
    const bf16* __restrict__ Dres, int ldd,
    bf16* __restrict__ Cb, float* __restrict__ Cf, int ldc,
    int N, int act)
{
  const int gslot = blockIdx.x * 4 + (threadIdx.x >> 6);
  const int rt = gslot / NGRP, cg = gslot - rt * NGRP;
  const int lane = threadIdx.x & 63, lr = lane & 15, lq = lane >> 4;
  const int m0 = rt * 16, n0 = cg * NT * 16;

  bf16x8 wf[NT][KS];
  #pragma unroll
  for (int nt = 0; nt < NT; ++nt) {
    int n = n0 + nt * 16 + lr;
    #pragma unroll
    for (int ks = 0; ks < KS; ++ks) {
      short8 s = {0,0,0,0,0,0,0,0};
      if (n < N) s = *(const short8*)&W[(size_t)n * ldw + ks * 32 + lq * 8];
      wf[nt][ks] = __builtin_bit_cast(bf16x8, s);
    }
  }
  f32x4 acc[NT];
  #pragma unroll
  for (int nt = 0; nt < NT; ++nt) acc[nt] = (f32x4){0.f, 0.f, 0.f, 0.f};
  #pragma unroll
  for (int ks = 0; ks < KS; ++ks) {
    bf16x8 af = __builtin_bit_cast(bf16x8,
        *(const short8*)&A[(size_t)(m0 + lr) * lda + ks * 32 + lq * 8]);
    #pragma unroll
    for (int nt = 0; nt < NT; ++nt)
      acc[nt] = __builtin_amdgcn_mfma_f32_16x16x32_bf16(af, wf[nt][ks], acc[nt], 0, 0, 0);
  }
  #pragma unroll
  for (int nt = 0; nt < NT; ++nt) {
    int n = n0 + nt * 16 + lr;
    if (n >= N) continue;
    float bv = bias ? bscale * bias[n] : 0.f;
    #pragma unroll
    for (int r = 0; r < 4; ++r) {
      int m = m0 + lq * 4 + r;
      float v = acc[nt][r] + bv;
      if (Dres) v += bf2f(*(const short*)&Dres[(size_t)m * ldd + n]);
      if (act) v = fmaxf(v, 0.f);
      if (F32OUT) Cf[(size_t)m * ldc + n] = v;
      else        Cb[(size_t)m * ldc + n] = __float2bfloat16(v);
    }
  }
}

// ================= wave-autonomous edge-message kernel =================
// gslot -> (node-group ng of 4 nodes, col-half ch of 48 cols). No LDS, no barriers.
// S[node] = sum_over_20_edges relu( relu(As[node]+An[nbr]) @ W1^T + b1 )
__global__ __launch_bounds__(256) void edge_k(
    const bf16* __restrict__ P,     // BN x 192: [As(+b0) | An]
    const bf16* __restrict__ w1bf,  // 96 x 96
    const float* __restrict__ b1,
    const int* __restrict__ edges,  // 81 x 20
    bf16* __restrict__ S)           // BN x 96
{
  const int gslot = blockIdx.x * 4 + (threadIdx.x >> 6);
  const int ng = gslot >> 1, ch = gslot & 1;
  const int lane = threadIdx.x & 63, lr = lane & 15, lq = lane >> 4;
  const int row0 = ng * 4, n0 = ch * 48;

  bf16x8 wf[3][3];
  #pragma unroll
  for (int nt = 0; nt < 3; ++nt) {
    int n = n0 + nt * 16 + lr;
    #pragma unroll
    for (int ks = 0; ks < 3; ++ks)
      wf[nt][ks] = __builtin_bit_cast(bf16x8, *(const short8*)&w1bf[n * 96 + ks * 32 + lq * 8]);
  }

  // per-mt source pointers (lane-private)
  const bf16* asp[5]; const bf16* anp[5];
  #pragma unroll
  for (int mt = 0; mt < 5; ++mt) {
    int row = mt * 16 + lr;          // 0..79
    int p = row / 20, j = row - p * 20;
    int gr = row0 + p;
    int b = gr / NNODE, i = gr - b * NNODE;
    int e = edges[i * KNB + j];
    asp[mt] = P + (size_t)gr * 192;
    anp[mt] = P + ((size_t)b * NNODE + e) * 192 + 96;
  }

  f32x4 acc[5][3];
  #pragma unroll
  for (int mt = 0; mt < 5; ++mt)
    #pragma unroll
    for (int nt = 0; nt < 3; ++nt) acc[mt][nt] = (f32x4){0.f, 0.f, 0.f, 0.f};

  #pragma unroll
  for (int ks = 0; ks < 3; ++ks) {
    const int koff = ks * 32 + lq * 8;
    #pragma unroll
    for (int mt = 0; mt < 5; ++mt) {
      short8 a8 = *(const short8*)(asp[mt] + koff);
      short8 n8 = *(const short8*)(anp[mt] + koff);
      short8 z;
      #pragma unroll
      for (int q = 0; q < 8; ++q)
        z[q] = f2bf(fmaxf(bf2f(a8[q]) + bf2f(n8[q]), 0.f));
      bf16x8 af = __builtin_bit_cast(bf16x8, z);
      #pragma unroll
      for (int nt = 0; nt < 3; ++nt)
        acc[mt][nt] = __builtin_amdgcn_mfma_f32_16x16x32_bf16(af, wf[nt][ks], acc[mt][nt], 0, 0, 0);
    }
  }

  float bv[3];
  #pragma unroll
  for (int nt = 0; nt < 3; ++nt) bv[nt] = b1[n0 + nt * 16 + lr];
  float nodeacc[4][3];
  #pragma unroll
  for (int pp = 0; pp < 4; ++pp)
    #pragma unroll
    for (int nt = 0; nt < 3; ++nt) nodeacc[pp][nt] = 0.f;
  #pragma unroll
  for (int mt = 0; mt < 5; ++mt)
    #pragma unroll
    for (int nt = 0; nt < 3; ++nt)
      #pragma unroll
      for (int r = 0; r < 4; ++r) {
        int row = mt * 16 + lq * 4 + r;
        int p = row / 20;
        float v = fmaxf(acc[mt][nt][r] + bv[nt], 0.f);
        #pragma unroll
        for (int pp = 0; pp < 4; ++pp)
          nodeacc[pp][nt] += (p == pp) ? v : 0.f;
      }
  #pragma unroll
  for (int pp = 0; pp < 4; ++pp)
    #pragma unroll
    for (int nt = 0; nt < 3; ++nt) {
      float v = nodeacc[pp][nt];
      v += __shfl_xor(v, 16, 64);
      v += __shfl_xor(v, 32, 64);
      if (lq == 0)
        S[(size_t)(row0 + pp) * 96 + n0 + nt * 16 + lr] = __float2bfloat16(v);
    }
}

// ================= wave-autonomous fused gates+LSTM =================
// gslot -> (row-tile rt, knt 0..5). Wave computes all 4 gates for 16 kcols,
// updates c (f32) and writes Hout (bf16). No LDS, no barriers.
__global__ __launch_bounds__(256) void lstm_k(
    const bf16* __restrict__ gin,   // BN x 96
    const bf16* __restrict__ Hin,   // BN x 96
    const bf16* __restrict__ wihb,  // 384 x 96
    const bf16* __restrict__ whhb,  // 384 x 96
    const float* __restrict__ bih, const float* __restrict__ bhh,
    float* __restrict__ c, bf16* __restrict__ Hout)
{
  const int gslot = blockIdx.x * 4 + (threadIdx.x >> 6);
  const int rt = gslot / 6, knt = gslot - rt * 6;
  const int lane = threadIdx.x & 63, lr = lane & 15, lq = lane >> 4;
  const int m0 = rt * 16, kcol = knt * 16 + lr;

  f32x4 acc[4];
  #pragma unroll
  for (int g = 0; g < 4; ++g) acc[g] = (f32x4){0.f, 0.f, 0.f, 0.f};

  #pragma unroll
  for (int ks = 0; ks < 3; ++ks) {
    const int koff = ks * 32 + lq * 8;
    bf16x8 gf_ = __builtin_bit_cast(bf16x8, *(const short8*)&gin[(size_t)(m0 + lr) * 96 + koff]);
    bf16x8 hf_ = __builtin_bit_cast(bf16x8, *(const short8*)&Hin[(size_t)(m0 + lr) * 96 + koff]);
    #pragma unroll
    for (int g = 0; g < 4; ++g) {
      bf16x8 wi = __builtin_bit_cast(bf16x8, *(const short8*)&wihb[(size_t)(g * 96 + kcol) * 96 + koff]);
      acc[g] = __builtin_amdgcn_mfma_f32_16x16x32_bf16(gf_, wi, acc[g], 0, 0, 0);
      bf16x8 wh = __builtin_bit_cast(bf16x8, *(const short8*)&whhb[(size_t)(g * 96 + kcol) * 96 + koff]);
      acc[g] = __builtin_amdgcn_mfma_f32_16x16x32_bf16(hf_, wh, acc[g], 0, 0, 0);
    }
  }

  float bv[4];
  #pragma unroll
  for (int g = 0; g < 4; ++g) bv[g] = bih[g * 96 + kcol] + bhh[g * 96 + kcol];
  #pragma unroll
  for (int r = 0; r < 4; ++r) {
    int m = m0 + lq * 4 + r;
    size_t idx = (size_t)m * 96 + kcol;
    float gi = acc[0][r] + bv[0];
    float gf = acc[1][r] + bv[1];
    float gg = acc[2][r] + bv[2];
    float go = acc[3][r] + bv[3];
    float si = 1.f / (1.f + expf(-gi));
    float sf = 1.f / (1.f + expf(-gf));
    float so = 1.f / (1.f + expf(-go));
    float tg = tanhf(gg);
    float cn = sf * c[idx] + si * tg;
    c[idx] = cn;
    Hout[idx] = __float2bfloat16(so * tanhf(cn));
  }
}

// ================= host side =================
typedef const bf16* cbp;
static inline void wg96(hipStream_t s, cbp A, cbp W, int ldw, const float* bias, float bsc,
                        cbp Dres, bf16* C, int act) {
  wgemm_k<2, 3, 3, false><<<972, 256, 0, s>>>(A, 96, W, ldw, bias, bsc, Dres, 96, C, nullptr, 96, 96, act);
}

extern "C" void kernel_launch(void* const* d_in, const int* in_sizes, int n_in,
                              void* d_out, int out_size, void* d_ws, size_t ws_size,
                              hipStream_t stream) {
  const float* embed   = (const float*)d_in[0];
  const float* in_w0   = (const float*)d_in[1];
  const float* in_b0   = (const float*)d_in[2];
  const float* in_w1   = (const float*)d_in[3];
  const float* in_b1   = (const float*)d_in[4];
  const float* in_w2   = (const float*)d_in[5];
  const float* in_b2   = (const float*)d_in[6];
  const float* f_w0    = (const float*)d_in[7];
  const float* f_b0    = (const float*)d_in[8];
  const float* f_w1    = (const float*)d_in[9];
  const float* f_b1    = (const float*)d_in[10];
  const float* f_w2    = (const float*)d_in[11];
  const float* f_b2    = (const float*)d_in[12];
  const float* g_w0    = (const float*)d_in[13];
  const float* g_b0    = (const float*)d_in[14];
  const float* g_w1    = (const float*)d_in[15];
  const float* g_b1    = (const float*)d_in[16];
  const float* g_w2    = (const float*)d_in[17];
  const float* g_b2    = (const float*)d_in[18];
  const float* wih     = (const float*)d_in[19];
  const float* whh     = (const float*)d_in[20];
  const float* bih     = (const float*)d_in[21];
  const float* bhh     = (const float*)d_in[22];
  const float* r_w0    = (const float*)d_in[23];
  const float* r_b0    = (const float*)d_in[24];
  const float* r_w1    = (const float*)d_in[25];
  const float* r_b1    = (const float*)d_in[26];
  const float* r_w2    = (const float*)d_in[27];
  const float* r_b2    = (const float*)d_in[28];
  const float* c0      = (const float*)d_in[29];
  const int*   grids   = (const int*)d_in[30];
  const int*   edges   = (const int*)d_in[31];

  float* out = (float*)d_out;
  const int iters = out_size / (BN * 9);   // = 4

  float* c    = (float*)d_ws;                        // BN*96 f32
  bf16* H0    = (bf16*)(c + (size_t)BN * 96);
  bf16* H1    = H0 + (size_t)BN * 96;
  bf16* Xg    = H1 + (size_t)BN * 96;
  bf16* P     = Xg + (size_t)BN * 96;                // BN*192
  bf16* Q     = P  + (size_t)BN * 192;
  bf16* R     = Q  + (size_t)BN * 96;
  bf16* emb   = R  + (size_t)BN * 96;                // BN*32
  bf16* w0pb  = emb + (size_t)BN * 32;               // 3072
  bf16* wfnb  = w0pb + 3072;                         // 18432
  bf16* inw1b = wfnb + 18432;
  bf16* inw2b = inw1b + 9216;
  bf16* fw1b  = inw2b + 9216;
  bf16* fw2b  = fw1b + 9216;
  bf16* gw0b  = fw2b + 9216;                         // 18432
  bf16* gw1b  = gw0b + 18432;
  bf16* gw2b  = gw1b + 9216;
  bf16* rw0b  = gw2b + 9216;
  bf16* rw1b  = rw0b + 9216;
  bf16* rw2b  = rw1b + 9216;                         // 864
  bf16* wihb  = rw2b + 864;                          // 36864
  bf16* whhb  = wihb + 36864;
  float* bias_fn = (float*)(whhb + 36864);           // 192 f32

  // ---- prologue ----
  prep_k<<<dim3(144, 15), 256, 0, stream>>>(
      in_w1, in_w2, f_w1, f_w2, g_w1, g_w2, r_w0, r_w1, r_w2, wih, whh, g_w0,
      f_w0, in_w0, f_b0,
      inw1b, inw2b, fw1b, fw2b, gw1b, gw2b, rw0b, rw1b, rw2b, wihb, whhb, gw0b,
      wfnb, w0pb, bias_fn);
  embed_k<<<(BN * 32) / 256, 256, 0, stream>>>(embed, grids, emb);
  // in-MLP: emb(32,pad) -> 96 -> 96 -> 96 => X in H0
  wgemm_k<2, 1, 3, false><<<972, 256, 0, stream>>>(emb, 32, w0pb, 32, in_b0, 1.f,
                                                   nullptr, 0, Q, nullptr, 96, 96, 1);
  wg96(stream, Q, inw1b, 96, in_b1, 1.f, nullptr, R, 1);
  wg96(stream, R, inw2b, 96, in_b2, 1.f, nullptr, H0, 0);
  // Xg = X @ g_w0[:, :96]^T + g_b0
  wg96(stream, H0, gw0b, 192, g_b0, 1.f, nullptr, Xg, 0);
  hipMemcpyAsync(c, c0, (size_t)BN * 96 * sizeof(float), hipMemcpyDeviceToDevice, stream);

  for (int it = 0; it < iters; ++it) {
    bf16* Hin  = (it & 1) ? H1 : H0;
    bf16* Hout = (it & 1) ? H0 : H1;
    // P = [As(+b0) | An] = Hin @ wfn^T + bias_fn   (N=192)
    wgemm_k<3, 3, 4, false><<<1296, 256, 0, stream>>>(Hin, 96, wfnb, 96, bias_fn, 1.f,
                                                      nullptr, 0, P, nullptr, 192, 192, 0);
    // S = sum_j relu(W1 relu(As + An[nbr]) + b1) -> Q
    edge_k<<<2592, 256, 0, stream>>>(P, fw1b, f_b1, edges, Q);
    // M = S @ f_w2^T + 20*f_b2 -> R
    wg96(stream, Q, fw2b, 96, f_b2, (float)KNB, nullptr, R, 0);
    // z1 = relu(M @ g_w0[:,96:]^T + Xg) -> Q
    wg96(stream, R, gw0b + 96, 192, nullptr, 0.f, Xg, Q, 1);
    // z2 = relu(z1 @ g_w1^T + g_b1) -> R
    wg96(stream, Q, gw1b, 96, g_b1, 1.f, nullptr, R, 1);
    // gin = z2 @ g_w2^T + g_b2 -> Q
    wg96(stream, R, gw2b, 96, g_b2, 1.f, nullptr, Q, 0);
    // gates + LSTM (c f32, Hout bf16)
    lstm_k<<<1944, 256, 0, stream>>>(Q, Hin, wihb, whhb, bih, bhh, c, Hout);
    // r-MLP: Hout -> 96 -> 96 -> 9
    wg96(stream, Hout, rw0b, 96, r_b0, 1.f, nullptr, Q, 1);
    wg96(stream, Q, rw1b, 96, r_b1, 1.f, nullptr, R, 1);
    wgemm_k<1, 3, 1, true><<<324, 256, 0, stream>>>(R, 96, rw2b, 96, r_b2, 1.f, nullptr, 0,
                                                    nullptr, out + (size_t)it * BN * 9, 9, 9, 0);
  }
}

// Round 6
// 370.722 us; speedup vs baseline: 7.4098x; 1.3112x over previous
//
#include <hip/hip_runtime.h>
#include <hip/hip_bf16.h>

typedef __hip_bfloat16 bf16;
typedef __attribute__((ext_vector_type(8))) short short8;
typedef __attribute__((ext_vector_type(8))) __bf16 bf16x8;
typedef __attribute__((ext_vector_type(4))) float f32x4;

#define BN 20736      // 256*81
#define NNODE 81
#define KNB 20

__device__ inline float bf2f(short s) {
  union { unsigned u; float f; } x; x.u = ((unsigned)(unsigned short)s) << 16; return x.f;
}
__device__ inline short f2bf(float f) {
  __hip_bfloat16 h = __float2bfloat16(f);
  return *reinterpret_cast<short*>(&h);
}

// ---------- shared device helpers for the fused transposing-chain kernels ----------
__device__ inline void load_w96(const bf16* __restrict__ W, int ldw, int lr, int lq,
                                bf16x8 wf[6][3]) {
  #pragma unroll
  for (int nt = 0; nt < 6; ++nt)
    #pragma unroll
    for (int ks = 0; ks < 3; ++ks)
      wf[nt][ks] = __builtin_bit_cast(bf16x8,
          *(const short8*)&W[(size_t)(nt * 16 + lr) * ldw + ks * 32 + lq * 8]);
}
__device__ inline void zacc6(f32x4 acc[6]) {
  #pragma unroll
  for (int nt = 0; nt < 6; ++nt) acc[nt] = (f32x4){0.f, 0.f, 0.f, 0.f};
}
__device__ inline void gemm96(const bf16x8 af[3], const bf16x8 wf[6][3], f32x4 acc[6]) {
  #pragma unroll
  for (int ks = 0; ks < 3; ++ks)
    #pragma unroll
    for (int nt = 0; nt < 6; ++nt)
      acc[nt] = __builtin_amdgcn_mfma_f32_16x16x32_bf16(af[ks], wf[nt][ks], acc[nt], 0, 0, 0);
}
// acc (col=lane&15, row=4*lq+r) -> xbuf[row][col] f32, stride 100 (2-way banks max)
__device__ inline void acc_to_xbuf(float* xw, const f32x4 acc[6], int lr, int lq) {
  #pragma unroll
  for (int nt = 0; nt < 6; ++nt)
    #pragma unroll
    for (int r = 0; r < 4; ++r)
      xw[(lq * 4 + r) * 100 + nt * 16 + lr] = acc[nt][r];
}
// read back as A-frags: af[ks] = bf16(act(x + bscale*bias[col] + resid[col]))
__device__ inline void xbuf_frag(const float* xw, int lr, int lq,
                                 const float* __restrict__ bias, float bscale,
                                 const bf16* __restrict__ residRow, int act,
                                 bf16x8 af[3]) {
  #pragma unroll
  for (int ks = 0; ks < 3; ++ks) {
    const int c0 = ks * 32 + lq * 8;
    float4 x0 = *(const float4*)&xw[lr * 100 + c0];
    float4 x1 = *(const float4*)&xw[lr * 100 + c0 + 4];
    float xv[8] = {x0.x, x0.y, x0.z, x0.w, x1.x, x1.y, x1.z, x1.w};
    if (bias) {
      float4 b0 = *(const float4*)&bias[c0];
      float4 b1 = *(const float4*)&bias[c0 + 4];
      float bv[8] = {b0.x, b0.y, b0.z, b0.w, b1.x, b1.y, b1.z, b1.w};
      #pragma unroll
      for (int j = 0; j < 8; ++j) xv[j] += bscale * bv[j];
    }
    if (residRow) {
      short8 r8 = *(const short8*)&residRow[c0];
      #pragma unroll
      for (int j = 0; j < 8; ++j) xv[j] += bf2f(r8[j]);
    }
    short8 o;
    #pragma unroll
    for (int j = 0; j < 8; ++j) {
      float v = xv[j];
      if (act) v = fmaxf(v, 0.f);
      o[j] = f2bf(v);
    }
    af[ks] = __builtin_bit_cast(bf16x8, o);
  }
}
__device__ inline void store_frag(bf16* dst, int lq, const bf16x8 af[3]) {
  #pragma unroll
  for (int ks = 0; ks < 3; ++ks)
    *(short8*)&dst[ks * 32 + lq * 8] = __builtin_bit_cast(short8, af[ks]);
}

// ================= prologue: convert/build all weights =================
__global__ __launch_bounds__(256) void prep_k(
    const float* in_w1, const float* in_w2, const float* f_w1, const float* f_w2,
    const float* g_w1, const float* g_w2, const float* r_w0, const float* r_w1,
    const float* r_w2, const float* wih, const float* whh, const float* g_w0,
    const float* f_w0, const float* in_w0, const float* f_b0,
    bf16* inw1b, bf16* inw2b, bf16* fw1b, bf16* fw2b,
    bf16* gw1b, bf16* gw2b, bf16* rw0b, bf16* rw1b,
    bf16* rw2b, bf16* wihb, bf16* whhb, bf16* gw0b,
    bf16* wfnb, bf16* w0pb, float* bias_fn)
{
  int idx = blockIdx.x * 256 + threadIdx.x;
  int y = blockIdx.y;
  const float* src = nullptr; bf16* dst = nullptr; int cnt = 0;
  switch (y) {
    case 0:  src = in_w1; dst = inw1b; cnt = 9216;  break;
    case 1:  src = in_w2; dst = inw2b; cnt = 9216;  break;
    case 2:  src = f_w1;  dst = fw1b;  cnt = 9216;  break;
    case 3:  src = f_w2;  dst = fw2b;  cnt = 9216;  break;
    case 4:  src = g_w1;  dst = gw1b;  cnt = 9216;  break;
    case 5:  src = g_w2;  dst = gw2b;  cnt = 9216;  break;
    case 6:  src = r_w0;  dst = rw0b;  cnt = 9216;  break;
    case 7:  src = r_w1;  dst = rw1b;  cnt = 9216;  break;
    case 8:  src = r_w2;  dst = rw2b;  cnt = 864;   break;
    case 9:  src = wih;   dst = wihb;  cnt = 36864; break;
    case 10: src = whh;   dst = whhb;  cnt = 36864; break;
    case 11: src = g_w0;  dst = gw0b;  cnt = 18432; break;
    case 12: {
      if (idx < 18432) {
        int n = idx / 96, k = idx - n * 96;
        float v = (n < 96) ? f_w0[n * 192 + k] : f_w0[(n - 96) * 192 + 96 + k];
        wfnb[idx] = __float2bfloat16(v);
      }
      return;
    }
    case 13: {
      if (idx < 3072) {
        int n = idx >> 5, k = idx & 31;
        w0pb[idx] = __float2bfloat16(k < 16 ? in_w0[n * 16 + k] : 0.f);
      }
      return;
    }
    default: {
      if (idx < 192) bias_fn[idx] = (idx < 96) ? f_b0[idx] : 0.f;
      return;
    }
  }
  if (idx < cnt) dst[idx] = __float2bfloat16(src[idx]);
}

__global__ __launch_bounds__(256) void embed_k(const float* __restrict__ embed,
                                               const int* __restrict__ grids,
                                               bf16* __restrict__ emb) {
  int idx = blockIdx.x * 256 + threadIdx.x;
  if (idx >= BN * 32) return;
  int r = idx >> 5, k = idx & 31;
  emb[idx] = __float2bfloat16(k < 16 ? embed[grids[r] * 16 + k] : 0.f);
}

// ================= fused input chain: emb -> X -> {Xg, P0} =================
__global__ __launch_bounds__(256) void fused_in_k(
    const bf16* __restrict__ emb, const bf16* __restrict__ w0pb, const float* __restrict__ in_b0,
    const bf16* __restrict__ inw1b, const float* __restrict__ in_b1,
    const bf16* __restrict__ inw2b, const float* __restrict__ in_b2,
    const bf16* __restrict__ gw0b, const float* __restrict__ g_b0,
    const bf16* __restrict__ wfnb, const float* __restrict__ bias_fn,
    bf16* __restrict__ X, bf16* __restrict__ Xg, bf16* __restrict__ P)
{
  __shared__ float xbuf[4 * 1600];
  const int t = threadIdx.x, w = t >> 6, lane = t & 63, lr = lane & 15, lq = lane >> 4;
  const int m0 = blockIdx.x * 64 + w * 16;
  float* xw = xbuf + w * 1600;
  bf16x8 wf[6][3]; f32x4 acc[6]; bf16x8 af[3];

  // stage0: emb(K=32) @ w0p^T + in_b0, relu
  bf16x8 a0 = __builtin_bit_cast(bf16x8, *(const short8*)&emb[(size_t)(m0 + lr) * 32 + lq * 8]);
  #pragma unroll
  for (int nt = 0; nt < 6; ++nt)
    wf[nt][0] = __builtin_bit_cast(bf16x8, *(const short8*)&w0pb[(size_t)(nt * 16 + lr) * 32 + lq * 8]);
  zacc6(acc);
  #pragma unroll
  for (int nt = 0; nt < 6; ++nt)
    acc[nt] = __builtin_amdgcn_mfma_f32_16x16x32_bf16(a0, wf[nt][0], acc[nt], 0, 0, 0);
  acc_to_xbuf(xw, acc, lr, lq); xbuf_frag(xw, lr, lq, in_b0, 1.f, nullptr, 1, af);
  // stage1
  load_w96(inw1b, 96, lr, lq, wf); zacc6(acc); gemm96(af, wf, acc);
  acc_to_xbuf(xw, acc, lr, lq); xbuf_frag(xw, lr, lq, in_b1, 1.f, nullptr, 1, af);
  // stage2 -> X
  load_w96(inw2b, 96, lr, lq, wf); zacc6(acc); gemm96(af, wf, acc);
  acc_to_xbuf(xw, acc, lr, lq);
  bf16x8 xf[3];
  xbuf_frag(xw, lr, lq, in_b2, 1.f, nullptr, 0, xf);
  store_frag(&X[(size_t)(m0 + lr) * 96], lq, xf);
  // Xg = X @ g_w0[:, :96]^T + g_b0
  load_w96(gw0b, 192, lr, lq, wf); zacc6(acc); gemm96(xf, wf, acc);
  acc_to_xbuf(xw, acc, lr, lq); xbuf_frag(xw, lr, lq, g_b0, 1.f, nullptr, 0, af);
  store_frag(&Xg[(size_t)(m0 + lr) * 96], lq, af);
  // P0 = X @ wfn^T + bias_fn (two 96-col halves)
  #pragma unroll
  for (int ph = 0; ph < 2; ++ph) {
    load_w96(wfnb + (size_t)ph * 96 * 96, 96, lr, lq, wf); zacc6(acc); gemm96(xf, wf, acc);
    acc_to_xbuf(xw, acc, lr, lq); xbuf_frag(xw, lr, lq, bias_fn + ph * 96, 1.f, nullptr, 0, af);
    store_frag(&P[(size_t)(m0 + lr) * 192 + ph * 96], lq, af);
  }
}

// ================= edge kernel: LDS-shared Z, 2 node-groups/block =================
__global__ __launch_bounds__(256) void edge_k(
    const bf16* __restrict__ P, const bf16* __restrict__ w1bf,
    const float* __restrict__ b1, const int* __restrict__ edges,
    bf16* __restrict__ S)
{
  __shared__ short zs[160 * 104];
  const int t = threadIdx.x;
  const int ng0 = blockIdx.x * 2;
  // build Z = relu(As + An[nbr]) for 8 nodes (160 rows), coalesced P reads
  for (int cc = t; cc < 160 * 12; cc += 256) {
    int zrow = cc / 12, c8 = cc - zrow * 12;
    int g = zrow >= 80 ? 1 : 0;
    int row = zrow - g * 80;
    int p = row / 20, j = row - p * 20;
    int gr = (ng0 + g) * 4 + p;
    int b = gr / NNODE, i = gr - b * NNODE;
    int e = edges[i * KNB + j];
    short8 a8 = *(const short8*)&P[(size_t)gr * 192 + c8 * 8];
    short8 n8 = *(const short8*)&P[((size_t)b * NNODE + e) * 192 + 96 + c8 * 8];
    short8 z;
    #pragma unroll
    for (int q = 0; q < 8; ++q)
      z[q] = f2bf(fmaxf(bf2f(a8[q]) + bf2f(n8[q]), 0.f));
    *(short8*)&zs[zrow * 104 + c8 * 8] = z;
  }
  __syncthreads();

  const int w = t >> 6, lane = t & 63, lr = lane & 15, lq = lane >> 4;
  const int g = w >> 1, ch = w & 1, n0 = ch * 48, zb = g * 80;
  const int row0 = (ng0 + g) * 4;

  bf16x8 wf[3][3];
  #pragma unroll
  for (int nt = 0; nt < 3; ++nt)
    #pragma unroll
    for (int ks = 0; ks < 3; ++ks)
      wf[nt][ks] = __builtin_bit_cast(bf16x8,
          *(const short8*)&w1bf[(size_t)(n0 + nt * 16 + lr) * 96 + ks * 32 + lq * 8]);

  f32x4 acc[5][3];
  #pragma unroll
  for (int mt = 0; mt < 5; ++mt)
    #pragma unroll
    for (int nt = 0; nt < 3; ++nt) acc[mt][nt] = (f32x4){0.f, 0.f, 0.f, 0.f};

  #pragma unroll
  for (int ks = 0; ks < 3; ++ks) {
    const int koff = ks * 32 + lq * 8;
    #pragma unroll
    for (int mt = 0; mt < 5; ++mt) {
      bf16x8 af = __builtin_bit_cast(bf16x8, *(const short8*)&zs[(zb + mt * 16 + lr) * 104 + koff]);
      #pragma unroll
      for (int nt = 0; nt < 3; ++nt)
        acc[mt][nt] = __builtin_amdgcn_mfma_f32_16x16x32_bf16(af, wf[nt][ks], acc[mt][nt], 0, 0, 0);
    }
  }

  float bv[3];
  #pragma unroll
  for (int nt = 0; nt < 3; ++nt) bv[nt] = b1[n0 + nt * 16 + lr];
  float nodeacc[4][3];
  #pragma unroll
  for (int pp = 0; pp < 4; ++pp)
    #pragma unroll
    for (int nt = 0; nt < 3; ++nt) nodeacc[pp][nt] = 0.f;
  #pragma unroll
  for (int mt = 0; mt < 5; ++mt)
    #pragma unroll
    for (int nt = 0; nt < 3; ++nt)
      #pragma unroll
      for (int r = 0; r < 4; ++r) {
        int row = mt * 16 + lq * 4 + r;
        int p = row / 20;
        float v = fmaxf(acc[mt][nt][r] + bv[nt], 0.f);
        #pragma unroll
        for (int pp = 0; pp < 4; ++pp)
          nodeacc[pp][nt] += (p == pp) ? v : 0.f;
      }
  #pragma unroll
  for (int pp = 0; pp < 4; ++pp)
    #pragma unroll
    for (int nt = 0; nt < 3; ++nt) {
      float v = nodeacc[pp][nt];
      v += __shfl_xor(v, 16, 64);
      v += __shfl_xor(v, 32, 64);
      if (lq == 0)
        S[(size_t)(row0 + pp) * 96 + n0 + nt * 16 + lr] = __float2bfloat16(v);
    }
}

// ================= fused MLP chain: S -> M -> z1 -> z2 -> gin =================
__global__ __launch_bounds__(256) void fused_mlp_k(
    const bf16* __restrict__ S, const bf16* __restrict__ fw2b, const float* __restrict__ f_b2,
    const bf16* __restrict__ gw0b, const bf16* __restrict__ Xg,
    const bf16* __restrict__ gw1b, const float* __restrict__ g_b1,
    const bf16* __restrict__ gw2b, const float* __restrict__ g_b2,
    bf16* __restrict__ gin)
{
  __shared__ float xbuf[4 * 1600];
  const int t = threadIdx.x, w = t >> 6, lane = t & 63, lr = lane & 15, lq = lane >> 4;
  const int m0 = blockIdx.x * 64 + w * 16;
  float* xw = xbuf + w * 1600;
  bf16x8 wf[6][3]; f32x4 acc[6]; bf16x8 af[3];

  // M = S @ f_w2^T + 20*f_b2
  #pragma unroll
  for (int ks = 0; ks < 3; ++ks)
    af[ks] = __builtin_bit_cast(bf16x8, *(const short8*)&S[(size_t)(m0 + lr) * 96 + ks * 32 + lq * 8]);
  load_w96(fw2b, 96, lr, lq, wf); zacc6(acc); gemm96(af, wf, acc);
  acc_to_xbuf(xw, acc, lr, lq); xbuf_frag(xw, lr, lq, f_b2, (float)KNB, nullptr, 0, af);
  // z1 = relu(M @ g_w0[:,96:]^T + Xg)
  load_w96(gw0b + 96, 192, lr, lq, wf); zacc6(acc); gemm96(af, wf, acc);
  acc_to_xbuf(xw, acc, lr, lq);
  xbuf_frag(xw, lr, lq, nullptr, 0.f, &Xg[(size_t)(m0 + lr) * 96], 1, af);
  // z2 = relu(z1 @ g_w1^T + g_b1)
  load_w96(gw1b, 96, lr, lq, wf); zacc6(acc); gemm96(af, wf, acc);
  acc_to_xbuf(xw, acc, lr, lq); xbuf_frag(xw, lr, lq, g_b1, 1.f, nullptr, 1, af);
  // gin = z2 @ g_w2^T + g_b2
  load_w96(gw2b, 96, lr, lq, wf); zacc6(acc); gemm96(af, wf, acc);
  acc_to_xbuf(xw, acc, lr, lq); xbuf_frag(xw, lr, lq, g_b2, 1.f, nullptr, 0, af);
  store_frag(&gin[(size_t)(m0 + lr) * 96], lq, af);
}

// ================= fused gates+LSTM (unchanged from R5) =================
__global__ __launch_bounds__(256) void lstm_k(
    const bf16* __restrict__ gin, const bf16* __restrict__ Hin,
    const bf16* __restrict__ wihb, const bf16* __restrict__ whhb,
    const float* __restrict__ bih, const float* __restrict__ bhh,
    float* __restrict__ c, bf16* __restrict__ Hout)
{
  const int gslot = blockIdx.x * 4 + (threadIdx.x >> 6);
  const int rt = gslot / 6, knt = gslot - rt * 6;
  const int lane = threadIdx.x & 63, lr = lane & 15, lq = lane >> 4;
  const int m0 = rt * 16, kcol = knt * 16 + lr;

  f32x4 acc[4];
  #pragma unroll
  for (int g = 0; g < 4; ++g) acc[g] = (f32x4){0.f, 0.f, 0.f, 0.f};
  #pragma unroll
  for (int ks = 0; ks < 3; ++ks) {
    const int koff = ks * 32 + lq * 8;
    bf16x8 gf_ = __builtin_bit_cast(bf16x8, *(const short8*)&gin[(size_t)(m0 + lr) * 96 + koff]);
    bf16x8 hf_ = __builtin_bit_cast(bf16x8, *(const short8*)&Hin[(size_t)(m0 + lr) * 96 + koff]);
    #pragma unroll
    for (int g = 0; g < 4; ++g) {
      bf16x8 wi = __builtin_bit_cast(bf16x8, *(const short8*)&wihb[(size_t)(g * 96 + kcol) * 96 + koff]);
      acc[g] = __builtin_amdgcn_mfma_f32_16x16x32_bf16(gf_, wi, acc[g], 0, 0, 0);
      bf16x8 wh = __builtin_bit_cast(bf16x8, *(const short8*)&whhb[(size_t)(g * 96 + kcol) * 96 + koff]);
      acc[g] = __builtin_amdgcn_mfma_f32_16x16x32_bf16(hf_, wh, acc[g], 0, 0, 0);
    }
  }
  float bv[4];
  #pragma unroll
  for (int g = 0; g < 4; ++g) bv[g] = bih[g * 96 + kcol] + bhh[g * 96 + kcol];
  #pragma unroll
  for (int r = 0; r < 4; ++r) {
    int m = m0 + lq * 4 + r;
    size_t idx = (size_t)m * 96 + kcol;
    float gi = acc[0][r] + bv[0];
    float gf = acc[1][r] + bv[1];
    float gg = acc[2][r] + bv[2];
    float go = acc[3][r] + bv[3];
    float si = 1.f / (1.f + expf(-gi));
    float sf = 1.f / (1.f + expf(-gf));
    float so = 1.f / (1.f + expf(-go));
    float tg = tanhf(gg);
    float cn = sf * c[idx] + si * tg;
    c[idx] = cn;
    Hout[idx] = __float2bfloat16(so * tanhf(cn));
  }
}

// ================= fused output chain: H -> {P_next, r-MLP -> out9} =================
__global__ __launch_bounds__(256) void fused_out_k(
    const bf16* __restrict__ H,
    const bf16* __restrict__ wfnb, const float* __restrict__ bias_fn, bf16* __restrict__ P,
    const bf16* __restrict__ rw0b, const float* __restrict__ r_b0,
    const bf16* __restrict__ rw1b, const float* __restrict__ r_b1,
    const bf16* __restrict__ rw2b, const float* __restrict__ r_b2,
    float* __restrict__ outp)
{
  __shared__ float xbuf[4 * 1600];
  const int t = threadIdx.x, w = t >> 6, lane = t & 63, lr = lane & 15, lq = lane >> 4;
  const int m0 = blockIdx.x * 64 + w * 16;
  float* xw = xbuf + w * 1600;
  bf16x8 wf[6][3]; f32x4 acc[6]; bf16x8 af[3];

  bf16x8 hf[3];
  #pragma unroll
  for (int ks = 0; ks < 3; ++ks)
    hf[ks] = __builtin_bit_cast(bf16x8, *(const short8*)&H[(size_t)(m0 + lr) * 96 + ks * 32 + lq * 8]);

  // P = H @ wfn^T + bias_fn (two halves)
  #pragma unroll
  for (int ph = 0; ph < 2; ++ph) {
    load_w96(wfnb + (size_t)ph * 96 * 96, 96, lr, lq, wf); zacc6(acc); gemm96(hf, wf, acc);
    acc_to_xbuf(xw, acc, lr, lq); xbuf_frag(xw, lr, lq, bias_fn + ph * 96, 1.f, nullptr, 0, af);
    store_frag(&P[(size_t)(m0 + lr) * 192 + ph * 96], lq, af);
  }
  // q1 = relu(H @ r_w0^T + b)
  load_w96(rw0b, 96, lr, lq, wf); zacc6(acc); gemm96(hf, wf, acc);
  acc_to_xbuf(xw, acc, lr, lq); xbuf_frag(xw, lr, lq, r_b0, 1.f, nullptr, 1, af);
  // q2 = relu(q1 @ r_w1^T + b)
  load_w96(rw1b, 96, lr, lq, wf); zacc6(acc); gemm96(af, wf, acc);
  acc_to_xbuf(xw, acc, lr, lq); xbuf_frag(xw, lr, lq, r_b1, 1.f, nullptr, 1, af);
  // out9 = q2 @ r_w2^T + b  (9 cols)
  bf16x8 w9[3];
  #pragma unroll
  for (int ks = 0; ks < 3; ++ks) {
    short8 s = {0, 0, 0, 0, 0, 0, 0, 0};
    if (lr < 9) s = *(const short8*)&rw2b[(size_t)lr * 96 + ks * 32 + lq * 8];
    w9[ks] = __builtin_bit_cast(bf16x8, s);
  }
  f32x4 a9 = (f32x4){0.f, 0.f, 0.f, 0.f};
  #pragma unroll
  for (int ks = 0; ks < 3; ++ks)
    a9 = __builtin_amdgcn_mfma_f32_16x16x32_bf16(af[ks], w9[ks], a9, 0, 0, 0);
  if (lr < 9) {
    float bb = r_b2[lr];
    #pragma unroll
    for (int r = 0; r < 4; ++r)
      outp[(size_t)(m0 + lq * 4 + r) * 9 + lr] = a9[r] + bb;
  }
}

// ================= host side =================
extern "C" void kernel_launch(void* const* d_in, const int* in_sizes, int n_in,
                              void* d_out, int out_size, void* d_ws, size_t ws_size,
                              hipStream_t stream) {
  const float* embed   = (const float*)d_in[0];
  const float* in_w0   = (const float*)d_in[1];
  const float* in_b0   = (const float*)d_in[2];
  const float* in_w1   = (const float*)d_in[3];
  const float* in_b1   = (const float*)d_in[4];
  const float* in_w2   = (const float*)d_in[5];
  const float* in_b2   = (const float*)d_in[6];
  const float* f_w0    = (const float*)d_in[7];
  const float* f_b0    = (const float*)d_in[8];
  const float* f_w1    = (const float*)d_in[9];
  const float* f_b1    = (const float*)d_in[10];
  const float* f_w2    = (const float*)d_in[11];
  const float* f_b2    = (const float*)d_in[12];
  const float* g_w0    = (const float*)d_in[13];
  const float* g_b0    = (const float*)d_in[14];
  const float* g_w1    = (const float*)d_in[15];
  const float* g_b1    = (const float*)d_in[16];
  const float* g_w2    = (const float*)d_in[17];
  const float* g_b2    = (const float*)d_in[18];
  const float* wih     = (const float*)d_in[19];
  const float* whh     = (const float*)d_in[20];
  const float* bih     = (const float*)d_in[21];
  const float* bhh     = (const float*)d_in[22];
  const float* r_w0    = (const float*)d_in[23];
  const float* r_b0    = (const float*)d_in[24];
  const float* r_w1    = (const float*)d_in[25];
  const float* r_b1    = (const float*)d_in[26];
  const float* r_w2    = (const float*)d_in[27];
  const float* r_b2    = (const float*)d_in[28];
  const float* c0      = (const float*)d_in[29];
  const int*   grids   = (const int*)d_in[30];
  const int*   edges   = (const int*)d_in[31];

  float* out = (float*)d_out;
  const int iters = out_size / (BN * 9);   // = 4

  float* c    = (float*)d_ws;                        // BN*96 f32
  bf16* H0    = (bf16*)(c + (size_t)BN * 96);
  bf16* H1    = H0 + (size_t)BN * 96;
  bf16* Xg    = H1 + (size_t)BN * 96;
  bf16* P     = Xg + (size_t)BN * 96;                // BN*192
  bf16* S     = P  + (size_t)BN * 192;
  bf16* gin   = S  + (size_t)BN * 96;
  bf16* emb   = gin + (size_t)BN * 96;               // BN*32
  bf16* w0pb  = emb + (size_t)BN * 32;               // 3072
  bf16* wfnb  = w0pb + 3072;                         // 18432
  bf16* inw1b = wfnb + 18432;
  bf16* inw2b = inw1b + 9216;
  bf16* fw1b  = inw2b + 9216;
  bf16* fw2b  = fw1b + 9216;
  bf16* gw0b  = fw2b + 9216;                         // 18432
  bf16* gw1b  = gw0b + 18432;
  bf16* gw2b  = gw1b + 9216;
  bf16* rw0b  = gw2b + 9216;
  bf16* rw1b  = rw0b + 9216;
  bf16* rw2b  = rw1b + 9216;                         // 864
  bf16* wihb  = rw2b + 864;                          // 36864
  bf16* whhb  = wihb + 36864;
  float* bias_fn = (float*)(whhb + 36864);           // 192 f32

  // ---- prologue ----
  prep_k<<<dim3(144, 15), 256, 0, stream>>>(
      in_w1, in_w2, f_w1, f_w2, g_w1, g_w2, r_w0, r_w1, r_w2, wih, whh, g_w0,
      f_w0, in_w0, f_b0,
      inw1b, inw2b, fw1b, fw2b, gw1b, gw2b, rw0b, rw1b, rw2b, wihb, whhb, gw0b,
      wfnb, w0pb, bias_fn);
  embed_k<<<(BN * 32) / 256, 256, 0, stream>>>(embed, grids, emb);
  fused_in_k<<<BN / 64, 256, 0, stream>>>(emb, w0pb, in_b0, inw1b, in_b1, inw2b, in_b2,
                                          gw0b, g_b0, wfnb, bias_fn, H0, Xg, P);
  hipMemcpyAsync(c, c0, (size_t)BN * 96 * sizeof(float), hipMemcpyDeviceToDevice, stream);

  for (int it = 0; it < iters; ++it) {
    bf16* Hin  = (it & 1) ? H1 : H0;
    bf16* Hout = (it & 1) ? H0 : H1;
    edge_k<<<BN / 8, 256, 0, stream>>>(P, fw1b, f_b1, edges, S);
    fused_mlp_k<<<BN / 64, 256, 0, stream>>>(S, fw2b, f_b2, gw0b, Xg, gw1b, g_b1,
                                             gw2b, g_b2, gin);
    lstm_k<<<BN * 6 / 64, 256, 0, stream>>>(gin, Hin, wihb, whhb, bih, bhh, c, Hout);
    fused_out_k<<<BN / 64, 256, 0, stream>>>(Hout, wfnb, bias_fn, P, rw0b, r_b0,
                                             rw1b, r_b1, rw2b, r_b2,
                                             out + (size_t)it * BN * 9);
  }
}

// Round 7
// 361.437 us; speedup vs baseline: 7.6002x; 1.0257x over previous
//
#include <hip/hip_runtime.h>
#include <hip/hip_bf16.h>

typedef __hip_bfloat16 bf16;
typedef __attribute__((ext_vector_type(8))) short short8;
typedef __attribute__((ext_vector_type(8))) __bf16 bf16x8;
typedef __attribute__((ext_vector_type(4))) float f32x4;

#define BN 20736      // 256*81
#define NNODE 81
#define KNB 20

__device__ inline float bf2f(short s) {
  union { unsigned u; float f; } x; x.u = ((unsigned)(unsigned short)s) << 16; return x.f;
}
__device__ inline short f2bf(float f) {
  __hip_bfloat16 h = __float2bfloat16(f);
  return *reinterpret_cast<short*>(&h);
}

// ---------- col-split helpers: wave owns 16 rows x 48 cols (n0 = ch*48) ----------
__device__ inline void zacc3(f32x4 acc[3]) {
  #pragma unroll
  for (int nt = 0; nt < 3; ++nt) acc[nt] = (f32x4){0.f, 0.f, 0.f, 0.f};
}
__device__ inline void load_w48(const bf16* __restrict__ W, int ldw, int n0, int lr, int lq,
                                bf16x8 wf[3][3]) {
  #pragma unroll
  for (int nt = 0; nt < 3; ++nt)
    #pragma unroll
    for (int ks = 0; ks < 3; ++ks)
      wf[nt][ks] = __builtin_bit_cast(bf16x8,
          *(const short8*)&W[(size_t)(n0 + nt * 16 + lr) * ldw + ks * 32 + lq * 8]);
}
__device__ inline void gemm48(const bf16x8 af[3], const bf16x8 wf[3][3], f32x4 acc[3]) {
  #pragma unroll
  for (int ks = 0; ks < 3; ++ks)
    #pragma unroll
    for (int nt = 0; nt < 3; ++nt)
      acc[nt] = __builtin_amdgcn_mfma_f32_16x16x32_bf16(af[ks], wf[nt][ks], acc[nt], 0, 0, 0);
}
// acc (row=4*lq+r, col=n0+nt*16+lr) -> xbuf f32, stride 100
__device__ inline void acc_store_cs(float* xw, const f32x4 acc[3], int lr, int lq, int n0) {
  #pragma unroll
  for (int nt = 0; nt < 3; ++nt)
    #pragma unroll
    for (int r = 0; r < 4; ++r)
      xw[(lq * 4 + r) * 100 + n0 + nt * 16 + lr] = acc[nt][r];
}
// read back full-width A-frags: af[ks] = bf16(act(x + bscale*bias[col] + resid[col]))
__device__ inline void xbuf_frag(const float* xw, int lr, int lq,
                                 const float* __restrict__ bias, float bscale,
                                 const bf16* __restrict__ residRow, int act,
                                 bf16x8 af[3]) {
  #pragma unroll
  for (int ks = 0; ks < 3; ++ks) {
    const int c0 = ks * 32 + lq * 8;
    float4 x0 = *(const float4*)&xw[lr * 100 + c0];
    float4 x1 = *(const float4*)&xw[lr * 100 + c0 + 4];
    float xv[8] = {x0.x, x0.y, x0.z, x0.w, x1.x, x1.y, x1.z, x1.w};
    if (bias) {
      float4 b0 = *(const float4*)&bias[c0];
      float4 b1 = *(const float4*)&bias[c0 + 4];
      float bv[8] = {b0.x, b0.y, b0.z, b0.w, b1.x, b1.y, b1.z, b1.w};
      #pragma unroll
      for (int j = 0; j < 8; ++j) xv[j] += bscale * bv[j];
    }
    if (residRow) {
      short8 r8 = *(const short8*)&residRow[c0];
      #pragma unroll
      for (int j = 0; j < 8; ++j) xv[j] += bf2f(r8[j]);
    }
    short8 o;
    #pragma unroll
    for (int j = 0; j < 8; ++j) {
      float v = xv[j];
      if (act) v = fmaxf(v, 0.f);
      o[j] = f2bf(v);
    }
    af[ks] = __builtin_bit_cast(bf16x8, o);
  }
}
__device__ inline void store_frag(bf16* dst, int lq, const bf16x8 af[3]) {
  #pragma unroll
  for (int ks = 0; ks < 3; ++ks)
    *(short8*)&dst[ks * 32 + lq * 8] = __builtin_bit_cast(short8, af[ks]);
}

// ================= prologue: convert/build all weights =================
__global__ __launch_bounds__(256) void prep_k(
    const float* in_w1, const float* in_w2, const float* f_w1, const float* f_w2,
    const float* g_w1, const float* g_w2, const float* r_w0, const float* r_w1,
    const float* r_w2, const float* wih, const float* whh, const float* g_w0,
    const float* f_w0, const float* in_w0, const float* f_b0,
    bf16* inw1b, bf16* inw2b, bf16* fw1b, bf16* fw2b,
    bf16* gw1b, bf16* gw2b, bf16* rw0b, bf16* rw1b,
    bf16* rw2b, bf16* wihb, bf16* whhb, bf16* gw0b,
    bf16* wfnb, bf16* w0pb, float* bias_fn)
{
  int idx = blockIdx.x * 256 + threadIdx.x;
  int y = blockIdx.y;
  const float* src = nullptr; bf16* dst = nullptr; int cnt = 0;
  switch (y) {
    case 0:  src = in_w1; dst = inw1b; cnt = 9216;  break;
    case 1:  src = in_w2; dst = inw2b; cnt = 9216;  break;
    case 2:  src = f_w1;  dst = fw1b;  cnt = 9216;  break;
    case 3:  src = f_w2;  dst = fw2b;  cnt = 9216;  break;
    case 4:  src = g_w1;  dst = gw1b;  cnt = 9216;  break;
    case 5:  src = g_w2;  dst = gw2b;  cnt = 9216;  break;
    case 6:  src = r_w0;  dst = rw0b;  cnt = 9216;  break;
    case 7:  src = r_w1;  dst = rw1b;  cnt = 9216;  break;
    case 8:  src = r_w2;  dst = rw2b;  cnt = 864;   break;
    case 9:  src = wih;   dst = wihb;  cnt = 36864; break;
    case 10: src = whh;   dst = whhb;  cnt = 36864; break;
    case 11: src = g_w0;  dst = gw0b;  cnt = 18432; break;
    case 12: {
      if (idx < 18432) {
        int n = idx / 96, k = idx - n * 96;
        float v = (n < 96) ? f_w0[n * 192 + k] : f_w0[(n - 96) * 192 + 96 + k];
        wfnb[idx] = __float2bfloat16(v);
      }
      return;
    }
    case 13: {
      if (idx < 3072) {
        int n = idx >> 5, k = idx & 31;
        w0pb[idx] = __float2bfloat16(k < 16 ? in_w0[n * 16 + k] : 0.f);
      }
      return;
    }
    default: {
      if (idx < 192) bias_fn[idx] = (idx < 96) ? f_b0[idx] : 0.f;
      return;
    }
  }
  if (idx < cnt) dst[idx] = __float2bfloat16(src[idx]);
}

__global__ __launch_bounds__(256) void embed_k(const float* __restrict__ embed,
                                               const int* __restrict__ grids,
                                               bf16* __restrict__ emb) {
  int idx = blockIdx.x * 256 + threadIdx.x;
  if (idx >= BN * 32) return;
  int r = idx >> 5, k = idx & 31;
  emb[idx] = __float2bfloat16(k < 16 ? embed[grids[r] * 16 + k] : 0.f);
}

// ================= fused input chain (col-split): emb -> X -> {Xg, P0} =================
__global__ __launch_bounds__(256) void fused_in_k(
    const bf16* __restrict__ emb, const bf16* __restrict__ w0pb, const float* __restrict__ in_b0,
    const bf16* __restrict__ inw1b, const float* __restrict__ in_b1,
    const bf16* __restrict__ inw2b, const float* __restrict__ in_b2,
    const bf16* __restrict__ gw0b, const float* __restrict__ g_b0,
    const bf16* __restrict__ wfnb, const float* __restrict__ bias_fn,
    bf16* __restrict__ X, bf16* __restrict__ Xg, bf16* __restrict__ P)
{
  __shared__ float xbuf[2][2][1600];
  const int t = threadIdx.x, w = t >> 6, lane = t & 63, lr = lane & 15, lq = lane >> 4;
  const int mh = w >> 1, ch = w & 1, n0 = ch * 48;
  const int m0 = blockIdx.x * 32 + mh * 16;
  float* x0 = xbuf[0][mh];
  float* x1 = xbuf[1][mh];
  bf16x8 wf[3][3]; f32x4 acc[3]; bf16x8 af[3];

  // stage0: emb(K=32) @ w0p^T + in_b0, relu
  bf16x8 a0 = __builtin_bit_cast(bf16x8, *(const short8*)&emb[(size_t)(m0 + lr) * 32 + lq * 8]);
  #pragma unroll
  for (int nt = 0; nt < 3; ++nt)
    wf[nt][0] = __builtin_bit_cast(bf16x8,
        *(const short8*)&w0pb[(size_t)(n0 + nt * 16 + lr) * 32 + lq * 8]);
  zacc3(acc);
  #pragma unroll
  for (int nt = 0; nt < 3; ++nt)
    acc[nt] = __builtin_amdgcn_mfma_f32_16x16x32_bf16(a0, wf[nt][0], acc[nt], 0, 0, 0);
  acc_store_cs(x0, acc, lr, lq, n0);
  __syncthreads();
  xbuf_frag(x0, lr, lq, in_b0, 1.f, nullptr, 1, af);
  // stage1
  load_w48(inw1b, 96, n0, lr, lq, wf); zacc3(acc); gemm48(af, wf, acc);
  acc_store_cs(x1, acc, lr, lq, n0);
  __syncthreads();
  xbuf_frag(x1, lr, lq, in_b1, 1.f, nullptr, 1, af);
  // stage2 -> X
  load_w48(inw2b, 96, n0, lr, lq, wf); zacc3(acc); gemm48(af, wf, acc);
  acc_store_cs(x0, acc, lr, lq, n0);
  __syncthreads();
  bf16x8 xf[3];
  xbuf_frag(x0, lr, lq, in_b2, 1.f, nullptr, 0, xf);
  if (ch == 0) store_frag(&X[(size_t)(m0 + lr) * 96], lq, xf);
  // stage3: Xg = X @ g_w0[:, :96]^T + g_b0
  load_w48(gw0b, 192, n0, lr, lq, wf); zacc3(acc); gemm48(xf, wf, acc);
  acc_store_cs(x1, acc, lr, lq, n0);
  __syncthreads();
  xbuf_frag(x1, lr, lq, g_b0, 1.f, nullptr, 0, af);
  if (ch == 0) store_frag(&Xg[(size_t)(m0 + lr) * 96], lq, af);
  // stage4/5: P halves = X @ wfn^T + bias_fn
  #pragma unroll
  for (int ph = 0; ph < 2; ++ph) {
    float* xb = ph ? x1 : x0;
    load_w48(wfnb + (size_t)ph * 96 * 96, 96, n0, lr, lq, wf); zacc3(acc); gemm48(xf, wf, acc);
    acc_store_cs(xb, acc, lr, lq, n0);
    __syncthreads();
    xbuf_frag(xb, lr, lq, bias_fn + ph * 96, 1.f, nullptr, 0, af);
    if (ch == 0) store_frag(&P[(size_t)(m0 + lr) * 192 + ph * 96], lq, af);
  }
}

// ================= edge kernel: LDS Z + fused M = S @ f_w2^T tail =================
__global__ __launch_bounds__(256) void edge_k(
    const bf16* __restrict__ P, const bf16* __restrict__ w1bf,
    const float* __restrict__ b1, const int* __restrict__ edges,
    const bf16* __restrict__ fw2b, const float* __restrict__ f_b2,
    bf16* __restrict__ M)
{
  __shared__ short zs[160 * 104];
  __shared__ short sbuf[16 * 104];
  const int t = threadIdx.x;
  const int ng0 = blockIdx.x * 2;
  // zero sbuf pad rows 8-15
  for (int i = t; i < 8 * 104; i += 256) sbuf[(8 + i / 104) * 104 + (i % 104)] = 0;
  // build Z = relu(As + An[nbr]) for 8 nodes (160 rows)
  for (int cc = t; cc < 160 * 12; cc += 256) {
    int zrow = cc / 12, c8 = cc - zrow * 12;
    int g = zrow >= 80 ? 1 : 0;
    int row = zrow - g * 80;
    int p = row / 20, j = row - p * 20;
    int gr = (ng0 + g) * 4 + p;
    int b = gr / NNODE, i = gr - b * NNODE;
    int e = edges[i * KNB + j];
    short8 a8 = *(const short8*)&P[(size_t)gr * 192 + c8 * 8];
    short8 n8 = *(const short8*)&P[((size_t)b * NNODE + e) * 192 + 96 + c8 * 8];
    short8 z;
    #pragma unroll
    for (int q = 0; q < 8; ++q)
      z[q] = f2bf(fmaxf(bf2f(a8[q]) + bf2f(n8[q]), 0.f));
    *(short8*)&zs[zrow * 104 + c8 * 8] = z;
  }
  __syncthreads();

  const int w = t >> 6, lane = t & 63, lr = lane & 15, lq = lane >> 4;
  const int g = w >> 1, ch = w & 1, n0 = ch * 48, zb = g * 80;

  bf16x8 wf[3][3];
  #pragma unroll
  for (int nt = 0; nt < 3; ++nt)
    #pragma unroll
    for (int ks = 0; ks < 3; ++ks)
      wf[nt][ks] = __builtin_bit_cast(bf16x8,
          *(const short8*)&w1bf[(size_t)(n0 + nt * 16 + lr) * 96 + ks * 32 + lq * 8]);

  f32x4 acc[5][3];
  #pragma unroll
  for (int mt = 0; mt < 5; ++mt)
    #pragma unroll
    for (int nt = 0; nt < 3; ++nt) acc[mt][nt] = (f32x4){0.f, 0.f, 0.f, 0.f};

  #pragma unroll
  for (int ks = 0; ks < 3; ++ks) {
    const int koff = ks * 32 + lq * 8;
    #pragma unroll
    for (int mt = 0; mt < 5; ++mt) {
      bf16x8 af = __builtin_bit_cast(bf16x8, *(const short8*)&zs[(zb + mt * 16 + lr) * 104 + koff]);
      #pragma unroll
      for (int nt = 0; nt < 3; ++nt)
        acc[mt][nt] = __builtin_amdgcn_mfma_f32_16x16x32_bf16(af, wf[nt][ks], acc[mt][nt], 0, 0, 0);
    }
  }

  float bv[3];
  #pragma unroll
  for (int nt = 0; nt < 3; ++nt) bv[nt] = b1[n0 + nt * 16 + lr];
  float nodeacc[4][3];
  #pragma unroll
  for (int pp = 0; pp < 4; ++pp)
    #pragma unroll
    for (int nt = 0; nt < 3; ++nt) nodeacc[pp][nt] = 0.f;
  #pragma unroll
  for (int mt = 0; mt < 5; ++mt)
    #pragma unroll
    for (int nt = 0; nt < 3; ++nt)
      #pragma unroll
      for (int r = 0; r < 4; ++r) {
        int row = mt * 16 + lq * 4 + r;
        int p = row / 20;
        float v = fmaxf(acc[mt][nt][r] + bv[nt], 0.f);
        #pragma unroll
        for (int pp = 0; pp < 4; ++pp)
          nodeacc[pp][nt] += (p == pp) ? v : 0.f;
      }
  // S rows (8 nodes) -> sbuf (bf16)
  #pragma unroll
  for (int pp = 0; pp < 4; ++pp)
    #pragma unroll
    for (int nt = 0; nt < 3; ++nt) {
      float v = nodeacc[pp][nt];
      v += __shfl_xor(v, 16, 64);
      v += __shfl_xor(v, 32, 64);
      if (lq == 0)
        sbuf[(g * 4 + pp) * 104 + n0 + nt * 16 + lr] = f2bf(v);
    }
  __syncthreads();
  // M = S @ f_w2^T + 20*f_b2  (waves 0-1 only; rows 8-15 of sbuf are zero)
  if (w < 2) {
    const int mn0 = w * 48;
    bf16x8 mwf[3][3];
    #pragma unroll
    for (int nt = 0; nt < 3; ++nt)
      #pragma unroll
      for (int ks = 0; ks < 3; ++ks)
        mwf[nt][ks] = __builtin_bit_cast(bf16x8,
            *(const short8*)&fw2b[(size_t)(mn0 + nt * 16 + lr) * 96 + ks * 32 + lq * 8]);
    f32x4 macc[3];
    zacc3(macc);
    #pragma unroll
    for (int ks = 0; ks < 3; ++ks) {
      bf16x8 af = __builtin_bit_cast(bf16x8, *(const short8*)&sbuf[lr * 104 + ks * 32 + lq * 8]);
      #pragma unroll
      for (int nt = 0; nt < 3; ++nt)
        macc[nt] = __builtin_amdgcn_mfma_f32_16x16x32_bf16(af, mwf[nt][ks], macc[nt], 0, 0, 0);
    }
    #pragma unroll
    for (int nt = 0; nt < 3; ++nt) {
      int col = mn0 + nt * 16 + lr;
      float bb = (float)KNB * f_b2[col];
      #pragma unroll
      for (int r = 0; r < 4; ++r) {
        int row = lq * 4 + r;
        if (row < 8)
          M[(size_t)(ng0 * 4 + row) * 96 + col] = __float2bfloat16(macc[nt][r] + bb);
      }
    }
  }
}

// ================= fused MLP chain (col-split): M -> z1 -> z2 -> gin =================
__global__ __launch_bounds__(256) void fused_mlp_k(
    const bf16* __restrict__ Min,
    const bf16* __restrict__ gw0b, const bf16* __restrict__ Xg,
    const bf16* __restrict__ gw1b, const float* __restrict__ g_b1,
    const bf16* __restrict__ gw2b, const float* __restrict__ g_b2,
    bf16* __restrict__ gin)
{
  __shared__ float xbuf[2][2][1600];
  const int t = threadIdx.x, w = t >> 6, lane = t & 63, lr = lane & 15, lq = lane >> 4;
  const int mh = w >> 1, ch = w & 1, n0 = ch * 48;
  const int m0 = blockIdx.x * 32 + mh * 16;
  float* x0 = xbuf[0][mh];
  float* x1 = xbuf[1][mh];
  bf16x8 wf[3][3]; f32x4 acc[3]; bf16x8 af[3];

  #pragma unroll
  for (int ks = 0; ks < 3; ++ks)
    af[ks] = __builtin_bit_cast(bf16x8,
        *(const short8*)&Min[(size_t)(m0 + lr) * 96 + ks * 32 + lq * 8]);
  // z1 = relu(M @ g_w0[:,96:]^T + Xg)
  load_w48(gw0b + 96, 192, n0, lr, lq, wf); zacc3(acc); gemm48(af, wf, acc);
  acc_store_cs(x0, acc, lr, lq, n0);
  __syncthreads();
  xbuf_frag(x0, lr, lq, nullptr, 0.f, &Xg[(size_t)(m0 + lr) * 96], 1, af);
  // z2 = relu(z1 @ g_w1^T + g_b1)
  load_w48(gw1b, 96, n0, lr, lq, wf); zacc3(acc); gemm48(af, wf, acc);
  acc_store_cs(x1, acc, lr, lq, n0);
  __syncthreads();
  xbuf_frag(x1, lr, lq, g_b1, 1.f, nullptr, 1, af);
  // gin = z2 @ g_w2^T + g_b2
  load_w48(gw2b, 96, n0, lr, lq, wf); zacc3(acc); gemm48(af, wf, acc);
  acc_store_cs(x0, acc, lr, lq, n0);
  __syncthreads();
  xbuf_frag(x0, lr, lq, g_b2, 1.f, nullptr, 0, af);
  if (ch == 0) store_frag(&gin[(size_t)(m0 + lr) * 96], lq, af);
}

// ================= fused gates+LSTM (unchanged) =================
__global__ __launch_bounds__(256) void lstm_k(
    const bf16* __restrict__ gin, const bf16* __restrict__ Hin,
    const bf16* __restrict__ wihb, const bf16* __restrict__ whhb,
    const float* __restrict__ bih, const float* __restrict__ bhh,
    float* __restrict__ c, bf16* __restrict__ Hout)
{
  const int gslot = blockIdx.x * 4 + (threadIdx.x >> 6);
  const int rt = gslot / 6, knt = gslot - rt * 6;
  const int lane = threadIdx.x & 63, lr = lane & 15, lq = lane >> 4;
  const int m0 = rt * 16, kcol = knt * 16 + lr;

  f32x4 acc[4];
  #pragma unroll
  for (int g = 0; g < 4; ++g) acc[g] = (f32x4){0.f, 0.f, 0.f, 0.f};
  #pragma unroll
  for (int ks = 0; ks < 3; ++ks) {
    const int koff = ks * 32 + lq * 8;
    bf16x8 gf_ = __builtin_bit_cast(bf16x8, *(const short8*)&gin[(size_t)(m0 + lr) * 96 + koff]);
    bf16x8 hf_ = __builtin_bit_cast(bf16x8, *(const short8*)&Hin[(size_t)(m0 + lr) * 96 + koff]);
    #pragma unroll
    for (int g = 0; g < 4; ++g) {
      bf16x8 wi = __builtin_bit_cast(bf16x8, *(const short8*)&wihb[(size_t)(g * 96 + kcol) * 96 + koff]);
      acc[g] = __builtin_amdgcn_mfma_f32_16x16x32_bf16(gf_, wi, acc[g], 0, 0, 0);
      bf16x8 wh = __builtin_bit_cast(bf16x8, *(const short8*)&whhb[(size_t)(g * 96 + kcol) * 96 + koff]);
      acc[g] = __builtin_amdgcn_mfma_f32_16x16x32_bf16(hf_, wh, acc[g], 0, 0, 0);
    }
  }
  float bv[4];
  #pragma unroll
  for (int g = 0; g < 4; ++g) bv[g] = bih[g * 96 + kcol] + bhh[g * 96 + kcol];
  #pragma unroll
  for (int r = 0; r < 4; ++r) {
    int m = m0 + lq * 4 + r;
    size_t idx = (size_t)m * 96 + kcol;
    float gi = acc[0][r] + bv[0];
    float gf = acc[1][r] + bv[1];
    float gg = acc[2][r] + bv[2];
    float go = acc[3][r] + bv[3];
    float si = 1.f / (1.f + expf(-gi));
    float sf = 1.f / (1.f + expf(-gf));
    float so = 1.f / (1.f + expf(-go));
    float tg = tanhf(gg);
    float cn = sf * c[idx] + si * tg;
    c[idx] = cn;
    Hout[idx] = __float2bfloat16(so * tanhf(cn));
  }
}

// ================= fused output chain (col-split): H -> {P_next, r-MLP -> out9} =================
__global__ __launch_bounds__(256) void fused_out_k(
    const bf16* __restrict__ H,
    const bf16* __restrict__ wfnb, const float* __restrict__ bias_fn, bf16* __restrict__ P,
    const bf16* __restrict__ rw0b, const float* __restrict__ r_b0,
    const bf16* __restrict__ rw1b, const float* __restrict__ r_b1,
    const bf16* __restrict__ rw2b, const float* __restrict__ r_b2,
    float* __restrict__ outp)
{
  __shared__ float xbuf[2][2][1600];
  const int t = threadIdx.x, w = t >> 6, lane = t & 63, lr = lane & 15, lq = lane >> 4;
  const int mh = w >> 1, ch = w & 1, n0 = ch * 48;
  const int m0 = blockIdx.x * 32 + mh * 16;
  float* x0 = xbuf[0][mh];
  float* x1 = xbuf[1][mh];
  bf16x8 wf[3][3]; f32x4 acc[3]; bf16x8 af[3];

  bf16x8 hf[3];
  #pragma unroll
  for (int ks = 0; ks < 3; ++ks)
    hf[ks] = __builtin_bit_cast(bf16x8,
        *(const short8*)&H[(size_t)(m0 + lr) * 96 + ks * 32 + lq * 8]);

  // P halves = H @ wfn^T + bias_fn
  #pragma unroll
  for (int ph = 0; ph < 2; ++ph) {
    float* xb = ph ? x1 : x0;
    load_w48(wfnb + (size_t)ph * 96 * 96, 96, n0, lr, lq, wf); zacc3(acc); gemm48(hf, wf, acc);
    acc_store_cs(xb, acc, lr, lq, n0);
    __syncthreads();
    xbuf_frag(xb, lr, lq, bias_fn + ph * 96, 1.f, nullptr, 0, af);
    if (ch == 0) store_frag(&P[(size_t)(m0 + lr) * 192 + ph * 96], lq, af);
  }
  // q1 = relu(H @ r_w0^T + b0)
  load_w48(rw0b, 96, n0, lr, lq, wf); zacc3(acc); gemm48(hf, wf, acc);
  acc_store_cs(x0, acc, lr, lq, n0);
  __syncthreads();
  xbuf_frag(x0, lr, lq, r_b0, 1.f, nullptr, 1, af);
  // q2 = relu(q1 @ r_w1^T + b1)
  load_w48(rw1b, 96, n0, lr, lq, wf); zacc3(acc); gemm48(af, wf, acc);
  acc_store_cs(x1, acc, lr, lq, n0);
  __syncthreads();
  xbuf_frag(x1, lr, lq, r_b1, 1.f, nullptr, 1, af);
  // out9 = q2 @ r_w2^T + b2  (ch==0 only)
  if (ch == 0) {
    bf16x8 w9[3];
    #pragma unroll
    for (int ks = 0; ks < 3; ++ks) {
      short8 s = {0, 0, 0, 0, 0, 0, 0, 0};
      if (lr < 9) s = *(const short8*)&rw2b[(size_t)lr * 96 + ks * 32 + lq * 8];
      w9[ks] = __builtin_bit_cast(bf16x8, s);
    }
    f32x4 a9 = (f32x4){0.f, 0.f, 0.f, 0.f};
    #pragma unroll
    for (int ks = 0; ks < 3; ++ks)
      a9 = __builtin_amdgcn_mfma_f32_16x16x32_bf16(af[ks], w9[ks], a9, 0, 0, 0);
    if (lr < 9) {
      float bb = r_b2[lr];
      #pragma unroll
      for (int r = 0; r < 4; ++r)
        outp[(size_t)(m0 + lq * 4 + r) * 9 + lr] = a9[r] + bb;
    }
  }
}

// ================= host side =================
extern "C" void kernel_launch(void* const* d_in, const int* in_sizes, int n_in,
                              void* d_out, int out_size, void* d_ws, size_t ws_size,
                              hipStream_t stream) {
  const float* embed   = (const float*)d_in[0];
  const float* in_w0   = (const float*)d_in[1];
  const float* in_b0   = (const float*)d_in[2];
  const float* in_w1   = (const float*)d_in[3];
  const float* in_b1   = (const float*)d_in[4];
  const float* in_w2   = (const float*)d_in[5];
  const float* in_b2   = (const float*)d_in[6];
  const float* f_w0    = (const float*)d_in[7];
  const float* f_b0    = (const float*)d_in[8];
  const float* f_w1    = (const float*)d_in[9];
  const float* f_b1    = (const float*)d_in[10];
  const float* f_w2    = (const float*)d_in[11];
  const float* f_b2    = (const float*)d_in[12];
  const float* g_w0    = (const float*)d_in[13];
  const float* g_b0    = (const float*)d_in[14];
  const float* g_w1    = (const float*)d_in[15];
  const float* g_b1    = (const float*)d_in[16];
  const float* g_w2    = (const float*)d_in[17];
  const float* g_b2    = (const float*)d_in[18];
  const float* wih     = (const float*)d_in[19];
  const float* whh     = (const float*)d_in[20];
  const float* bih     = (const float*)d_in[21];
  const float* bhh     = (const float*)d_in[22];
  const float* r_w0    = (const float*)d_in[23];
  const float* r_b0    = (const float*)d_in[24];
  const float* r_w1    = (const float*)d_in[25];
  const float* r_b1    = (const float*)d_in[26];
  const float* r_w2    = (const float*)d_in[27];
  const float* r_b2    = (const float*)d_in[28];
  const float* c0      = (const float*)d_in[29];
  const int*   grids   = (const int*)d_in[30];
  const int*   edges   = (const int*)d_in[31];

  float* out = (float*)d_out;
  const int iters = out_size / (BN * 9);   // = 4

  float* c    = (float*)d_ws;                        // BN*96 f32
  bf16* H0    = (bf16*)(c + (size_t)BN * 96);
  bf16* H1    = H0 + (size_t)BN * 96;
  bf16* Xg    = H1 + (size_t)BN * 96;
  bf16* P     = Xg + (size_t)BN * 96;                // BN*192
  bf16* Mb    = P  + (size_t)BN * 192;
  bf16* gin   = Mb + (size_t)BN * 96;
  bf16* emb   = gin + (size_t)BN * 96;               // BN*32
  bf16* w0pb  = emb + (size_t)BN * 32;               // 3072
  bf16* wfnb  = w0pb + 3072;                         // 18432
  bf16* inw1b = wfnb + 18432;
  bf16* inw2b = inw1b + 9216;
  bf16* fw1b  = inw2b + 9216;
  bf16* fw2b  = fw1b + 9216;
  bf16* gw0b  = fw2b + 9216;                         // 18432
  bf16* gw1b  = gw0b + 18432;
  bf16* gw2b  = gw1b + 9216;
  bf16* rw0b  = gw2b + 9216;
  bf16* rw1b  = rw0b + 9216;
  bf16* rw2b  = rw1b + 9216;                         // 864
  bf16* wihb  = rw2b + 864;                          // 36864
  bf16* whhb  = wihb + 36864;
  float* bias_fn = (float*)(whhb + 36864);           // 192 f32

  // ---- prologue ----
  prep_k<<<dim3(144, 15), 256, 0, stream>>>(
      in_w1, in_w2, f_w1, f_w2, g_w1, g_w2, r_w0, r_w1, r_w2, wih, whh, g_w0,
      f_w0, in_w0, f_b0,
      inw1b, inw2b, fw1b, fw2b, gw1b, gw2b, rw0b, rw1b, rw2b, wihb, whhb, gw0b,
      wfnb, w0pb, bias_fn);
  embed_k<<<(BN * 32) / 256, 256, 0, stream>>>(embed, grids, emb);
  fused_in_k<<<BN / 32, 256, 0, stream>>>(emb, w0pb, in_b0, inw1b, in_b1, inw2b, in_b2,
                                          gw0b, g_b0, wfnb, bias_fn, H0, Xg, P);
  hipMemcpyAsync(c, c0, (size_t)BN * 96 * sizeof(float), hipMemcpyDeviceToDevice, stream);

  for (int it = 0; it < iters; ++it) {
    bf16* Hin  = (it & 1) ? H1 : H0;
    bf16* Hout = (it & 1) ? H0 : H1;
    edge_k<<<BN / 8, 256, 0, stream>>>(P, fw1b, f_b1, edges, fw2b, f_b2, Mb);
    fused_mlp_k<<<BN / 32, 256, 0, stream>>>(Mb, gw0b, Xg, gw1b, g_b1, gw2b, g_b2, gin);
    lstm_k<<<BN * 6 / 64, 256, 0, stream>>>(gin, Hin, wihb, whhb, bih, bhh, c, Hout);
    fused_out_k<<<BN / 32, 256, 0, stream>>>(Hout, wfnb, bias_fn, P, rw0b, r_b0,
                                             rw1b, r_b1, rw2b, r_b2,
                                             out + (size_t)it * BN * 9);
  }
}